// Round 4
// baseline (490.440 us; speedup 1.0000x reference)
//
#include <hip/hip_runtime.h>
#include <cstdint>
#include <cstddef>

typedef __attribute__((ext_vector_type(8))) short short8;
typedef __attribute__((ext_vector_type(4))) short short4v;
typedef __attribute__((ext_vector_type(4))) float f32x4;
typedef __attribute__((ext_vector_type(2))) unsigned uint2v;

#define DEV static __device__ __forceinline__

DEV short f2bf(float f) {
    unsigned u = __builtin_bit_cast(unsigned, f);
    unsigned r = (u + 0x7fffu + ((u >> 16) & 1u)) >> 16;
    return (short)r;
}

DEV unsigned cvt_pk_bf16(float a, float b) {
    unsigned r;
    asm("v_cvt_pk_bf16_f32 %0, %1, %2" : "=v"(r) : "v"(a), "v"(b));
    return r;
}

DEV float exp2_hw(float x) {
    float r;
    asm("v_exp_f32 %0, %1" : "=v"(r) : "v"(x));
    return r;
}

DEV void gld16(const void* g, void* l) {
    __builtin_amdgcn_global_load_lds((const __attribute__((address_space(1))) void*)g,
                                     (__attribute__((address_space(3))) void*)l, 16, 0, 0);
}

#define MFMA(c, a, b) asm volatile("v_mfma_f32_16x16x32_bf16 %0, %1, %2, %0" : "+v"(c) : "v"(a), "v"(b))
#define BAR() asm volatile("s_barrier" ::: "memory")

// ---------------- weight fp32 -> bf16 convert ----------------
__global__ __launch_bounds__(256) void cvt_weights(
    const float* __restrict__ wq, const float* __restrict__ wk,
    const float* __restrict__ wv, const float* __restrict__ wo,
    const float* __restrict__ w1, const float* __restrict__ w2,
    short* __restrict__ dst) {
    long long gid = (long long)blockIdx.x * 256 + threadIdx.x;
    long long i4 = gid * 4;
    const float* src; long long loc;
    if (i4 < (4LL << 20)) {
        int s = (int)(i4 >> 20);
        src = (s == 0) ? wq : (s == 1) ? wk : (s == 2) ? wv : wo;
        loc = i4 & ((1LL << 20) - 1);
    } else {
        long long r = i4 - (4LL << 20);
        int s = (int)(r >> 22);
        src = s ? w2 : w1;
        loc = r & ((1LL << 22) - 1);
    }
    float4 v = *(const float4*)(src + loc);
    short4v o;
    o.x = f2bf(v.x); o.y = f2bf(v.y); o.z = f2bf(v.z); o.w = f2bf(v.w);
    *(short4v*)(dst + i4) = o;
}

// ---------------- LayerNorm (D=1024), fp32 in -> bf16 out ----------------
__global__ __launch_bounds__(256) void ln_bf16(const float* __restrict__ x,
                                               const float* __restrict__ g,
                                               const float* __restrict__ bt,
                                               short* __restrict__ out) {
    int row = blockIdx.x;
    const float4* xr = (const float4*)(x + (size_t)row * 1024);
    float4 v = xr[threadIdx.x];
    float s  = v.x + v.y + v.z + v.w;
    float s2 = v.x*v.x + v.y*v.y + v.z*v.z + v.w*v.w;
    #pragma unroll
    for (int m = 1; m < 64; m <<= 1) { s += __shfl_xor(s, m); s2 += __shfl_xor(s2, m); }
    __shared__ float red[8];
    int wid = threadIdx.x >> 6;
    if ((threadIdx.x & 63) == 0) { red[wid] = s; red[4 + wid] = s2; }
    __syncthreads();
    s  = red[0] + red[1] + red[2] + red[3];
    s2 = red[4] + red[5] + red[6] + red[7];
    float mu  = s * (1.0f / 1024.0f);
    float var = fmaxf(s2 * (1.0f / 1024.0f) - mu * mu, 0.0f);
    float rs  = rsqrtf(var + 1e-5f);
    float4 gv = ((const float4*)g)[threadIdx.x];
    float4 bv = ((const float4*)bt)[threadIdx.x];
    short4v o;
    o.x = f2bf((v.x - mu) * rs * gv.x + bv.x);
    o.y = f2bf((v.y - mu) * rs * gv.y + bv.y);
    o.z = f2bf((v.z - mu) * rs * gv.z + bv.z);
    o.w = f2bf((v.w - mu) * rs * gv.w + bv.w);
    *(short4v*)(out + (size_t)row * 1024 + (size_t)threadIdx.x * 4) = o;
}

// ================= 256x256 8-wave 8-phase GEMM core =================
// C[bm*256.., bn*256..] = A[M,K(lda)] * B[N,K(ldb)]^T, bf16 in, fp32 acc.
// 512 thr = 8 waves (2M x 4N), wave tile 128x64 (8x4 frags).
// LDS: 2 dbuf x {A0,A1,B0,B1 half-regions of 128x64}, 16B-slot XOR swizzle (slot^=row&7).
// 4 phases/K-tile = (Mquad x kslot); per phase: 8 ds_read_b128 + 1 half-tile stage + BAR + 16 MFMA + BAR.
// Stage stream: p0:A0(t+1) p1:A1(t+1) p2:B0(t+2) p3:B1(t+2); vmcnt(4) once per tile.
// MODE 1: fp32 out = acc (+resid if non-null). MODE 2: bf16 gelu. MODE 3: bf16 * osc.
template<int MODE>
DEV void gemm_core(const short* __restrict__ A, const short* __restrict__ B,
                   void* __restrict__ out, const float* __restrict__ resid,
                   int N, int K, int lda, int ldb, float osc, int bm, int bn) {
    __shared__ short lds[2 * 32768];
    const int tid = threadIdx.x;
    const int row0 = bm << 8, col0 = bn << 8;
    const int wid = tid >> 6, lane = tid & 63;
    const int wm = wid >> 2, wn = wid & 3;
    const int lr = lane & 15, lg = lane >> 4;
    const int NK = K >> 6;

    auto stage = [&](int kt, int which) {
        int d = kt & 1;
        const short* src; int rb; int ld;
        if (which < 2) { src = A; rb = row0; ld = lda; } else { src = B; rb = col0; ld = ldb; }
        int rhalf = (which & 1) << 7;
        short* dst = lds + d * 32768 + which * 8192;
        #pragma unroll
        for (int l = 0; l < 2; ++l) {
            int g = l * 512 + tid;
            int r = g >> 3, c = g & 7;
            gld16(src + (size_t)(rb + rhalf + r) * ld + kt * 64 + ((c ^ (r & 7)) << 3),
                  dst + g * 8);
        }
    };

    f32x4 acc[8][4] = {};

    // prologue: tile0 fully + B halves of tile1
    stage(0, 0); stage(0, 1); stage(0, 2); stage(0, 3);
    if (NK > 1) {
        stage(1, 2); stage(1, 3);
        asm volatile("s_waitcnt vmcnt(4)" ::: "memory");
    } else {
        asm volatile("s_waitcnt vmcnt(0)" ::: "memory");
    }
    BAR();

    const int rBbase = (wn & 1) << 6;
    for (int t = 0; t < NK; ++t) {
        const short* bufA = lds + (t & 1) * 32768 + wm * 8192;
        const short* bufB = lds + (t & 1) * 32768 + 16384 + (wn >> 1) * 8192;
        bool st1 = (t + 1) < NK, st2 = (t + 2) < NK;
        short8 bf2[2][4];

        // ---- p0: mq=0 ks=0 ----
        {
            short8 af[4];
            #pragma unroll
            for (int i = 0; i < 4; ++i) {
                int r = i * 16 + lr;
                af[i] = *(const short8*)(bufA + r * 64 + ((lg ^ (r & 7)) << 3));
            }
            #pragma unroll
            for (int j = 0; j < 4; ++j) {
                int rB = rBbase + j * 16 + lr;
                bf2[0][j] = *(const short8*)(bufB + rB * 64 + ((lg ^ (rB & 7)) << 3));
            }
            if (st1) stage(t + 1, 0);
            BAR();
            __builtin_amdgcn_s_setprio(1);
            #pragma unroll
            for (int i = 0; i < 4; ++i)
                #pragma unroll
                for (int j = 0; j < 4; ++j)
                    MFMA(acc[i][j], af[i], bf2[0][j]);
            __builtin_amdgcn_s_setprio(0);
            BAR();
        }
        // ---- p1: mq=0 ks=1 ----
        {
            short8 af[4];
            #pragma unroll
            for (int i = 0; i < 4; ++i) {
                int r = i * 16 + lr;
                af[i] = *(const short8*)(bufA + r * 64 + (((4 + lg) ^ (r & 7)) << 3));
            }
            #pragma unroll
            for (int j = 0; j < 4; ++j) {
                int rB = rBbase + j * 16 + lr;
                bf2[1][j] = *(const short8*)(bufB + rB * 64 + (((4 + lg) ^ (rB & 7)) << 3));
            }
            if (st1) stage(t + 1, 1);
            BAR();
            __builtin_amdgcn_s_setprio(1);
            #pragma unroll
            for (int i = 0; i < 4; ++i)
                #pragma unroll
                for (int j = 0; j < 4; ++j)
                    MFMA(acc[i][j], af[i], bf2[1][j]);
            __builtin_amdgcn_s_setprio(0);
            BAR();
        }
        // ---- p2: mq=1 ks=0 ----
        {
            short8 af[4];
            #pragma unroll
            for (int i = 0; i < 4; ++i) {
                int r = 64 + i * 16 + lr;
                af[i] = *(const short8*)(bufA + r * 64 + ((lg ^ (r & 7)) << 3));
            }
            if (st2) stage(t + 2, 2);
            BAR();
            __builtin_amdgcn_s_setprio(1);
            #pragma unroll
            for (int i = 0; i < 4; ++i)
                #pragma unroll
                for (int j = 0; j < 4; ++j)
                    MFMA(acc[4 + i][j], af[i], bf2[0][j]);
            __builtin_amdgcn_s_setprio(0);
            BAR();
        }
        // ---- p3: mq=1 ks=1 ----
        {
            short8 af[4];
            #pragma unroll
            for (int i = 0; i < 4; ++i) {
                int r = 64 + i * 16 + lr;
                af[i] = *(const short8*)(bufA + r * 64 + (((4 + lg) ^ (r & 7)) << 3));
            }
            if (st2) stage(t + 2, 3);
            BAR();
            __builtin_amdgcn_s_setprio(1);
            #pragma unroll
            for (int i = 0; i < 4; ++i)
                #pragma unroll
                for (int j = 0; j < 4; ++j)
                    MFMA(acc[4 + i][j], af[i], bf2[1][j]);
            __builtin_amdgcn_s_setprio(0);
            if (st2)      asm volatile("s_waitcnt vmcnt(4)" ::: "memory");
            else if (st1) asm volatile("s_waitcnt vmcnt(0)" ::: "memory");
            BAR();
        }
    }
    asm volatile("s_nop 7\n\ts_nop 7");

    int orow0 = row0 + wm * 128, ocol0 = col0 + wn * 64;
    #pragma unroll
    for (int i = 0; i < 8; ++i)
        #pragma unroll
        for (int j = 0; j < 4; ++j)
            #pragma unroll
            for (int r = 0; r < 4; ++r) {
                int gr = orow0 + i * 16 + lg * 4 + r;
                int gc = ocol0 + j * 16 + lr;
                size_t off = (size_t)gr * N + gc;
                float v = acc[i][j][r];
                if constexpr (MODE == 1) {
                    ((float*)out)[off] = resid ? v + resid[off] : v;
                } else if constexpr (MODE == 2) {
                    float tg = 0.5f * v * (1.0f + erff(v * 0.70710678118f));
                    ((short*)out)[off] = f2bf(tg);
                } else {
                    ((short*)out)[off] = f2bf(v * osc);
                }
            }
}

// fused Q + K + Vt projections (384 blocks)
__global__ __launch_bounds__(512, 2) void gemm_qkv(
    const short* __restrict__ XN, const short* __restrict__ CN,
    const short* __restrict__ Wq, const short* __restrict__ Wk, const short* __restrict__ Wv,
    short* __restrict__ QB, short* __restrict__ KB, short* __restrict__ VT, float qscale) {
    int sid = (blockIdx.x & 7) * 48 + (blockIdx.x >> 3);
    int sub = sid >> 7, i = sid & 127;
    const short *A, *B; short* o; float osc; int N, bm, bn;
    if (sub == 0)      { A = XN; B = Wq; o = QB; osc = qscale; N = 1024; bm = i >> 2; bn = i & 3; }
    else if (sub == 1) { A = CN; B = Wk; o = KB; osc = 1.0f;   N = 1024; bm = i >> 2; bn = i & 3; }
    else               { A = Wv; B = CN; o = VT; osc = 1.0f;   N = 8192; bm = i >> 5; bn = i & 31; }
    gemm_core<3>(A, B, o, nullptr, N, 1024, 1024, 1024, osc, bm, bn);
}

// standalone GEMM
template<int MODE>
__global__ __launch_bounds__(512, 2) void gemm_std(const short* __restrict__ A,
                                                   const short* __restrict__ B,
                                                   void* __restrict__ out,
                                                   const float* __restrict__ resid,
                                                   int N, int K, float osc) {
    int cpx = gridDim.x >> 3;
    int sid = (blockIdx.x & 7) * cpx + (blockIdx.x >> 3);
    int nbn = N >> 8;
    int bm = sid / nbn, bn = sid % nbn;
    gemm_core<MODE>(A, B, out, resid, N, K, K, K, osc, bm, bn);
}

// FF2 split-K: half 0 -> dOut = acc + X2 ; half 1 -> P2 = acc   (256 blocks)
__global__ __launch_bounds__(512, 2) void gemm_ff2(const short* __restrict__ F1,
                                                   const short* __restrict__ W2,
                                                   float* __restrict__ dOut,
                                                   float* __restrict__ P2,
                                                   const float* __restrict__ X2) {
    int sid = (blockIdx.x & 7) * 32 + (blockIdx.x >> 3);
    int h = sid >> 7, i = sid & 127;
    int bm = i >> 2, bn = i & 3;
    const short* A = F1 + h * 2048;
    const short* B = W2 + h * 2048;
    float* o = h ? P2 : dOut;
    const float* r = h ? nullptr : X2;
    gemm_core<1>(A, B, o, r, 1024, 2048, 4096, 4096, 1.0f, bm, bn);
}

__global__ __launch_bounds__(256) void add_f32(float* __restrict__ dst,
                                               const float* __restrict__ src, int n4) {
    int i = blockIdx.x * 256 + threadIdx.x;
    int stride = gridDim.x * 256;
    for (; i < n4; i += stride) {
        float4 a = ((const float4*)dst)[i];
        float4 b = ((const float4*)src)[i];
        a.x += b.x; a.y += b.y; a.z += b.z; a.w += b.w;
        ((float4*)dst)[i] = a;
    }
}

// ---------------- Flash attention (swapped-QK^T, in-register softmax) ----------------
__global__ __launch_bounds__(256) void attn(const short* __restrict__ Q,
                                            const short* __restrict__ K,
                                            const short* __restrict__ Vt,
                                            short* __restrict__ O) {
    __shared__ short lK[64 * 64];
    __shared__ short lV[64 * 64];
    __shared__ short lP[4][32 * 64];
    int tid = threadIdx.x;
    int qt = blockIdx.x & 15;
    int bh = blockIdx.x >> 4;
    int b = bh >> 4, h = bh & 15;
    int wid = tid >> 6, lane = tid & 63;
    int lr = lane & 15, lg = lane >> 4;
    int q0 = qt * 128 + wid * 32;

    short8 qf[2][2];
    #pragma unroll
    for (int fm = 0; fm < 2; ++fm)
        #pragma unroll
        for (int kb = 0; kb < 2; ++kb) {
            size_t roff = (size_t)(b * 2048 + q0 + fm * 16 + lr) * 1024 + h * 64 + kb * 32 + lg * 8;
            qf[fm][kb] = *(const short8*)(Q + roff);
        }

    f32x4 oacc[2][4] = {};
    float mrow[2] = { -1e30f, -1e30f };
    float lrs[2]  = { 0.0f, 0.0f };

    const short* Kb = K + (size_t)(b * 2048) * 1024 + h * 64;
    const short* Vb = Vt + (size_t)(h * 64) * 8192 + b * 2048;
    short* Pw = lP[wid];
    int albase = (lane & 48) >> 2;

    for (int st = 0; st < 32; ++st) {
        #pragma unroll
        for (int c = 0; c < 2; ++c) {
            int idx = c * 256 + tid;
            int r = idx >> 3, sp = idx & 7;
            int sl = sp ^ (r & 7);
            gld16(Kb + (size_t)(st * 64 + r) * 1024 + sl * 8, &lK[idx * 8]);
            gld16(Vb + (size_t)r * 8192 + st * 64 + sl * 8, &lV[idx * 8]);
        }
        __syncthreads();

        f32x4 sc2[4][2] = {};
        #pragma unroll
        for (int kb = 0; kb < 2; ++kb) {
            short8 kf[4];
            #pragma unroll
            for (int fn = 0; fn < 4; ++fn) {
                int kr = fn * 16 + lr;
                kf[fn] = *(const short8*)(lK + kr * 64 + (((kb * 4 + lg) ^ (kr & 7)) << 3));
            }
            #pragma unroll
            for (int fn = 0; fn < 4; ++fn)
                #pragma unroll
                for (int fm = 0; fm < 2; ++fm)
                    MFMA(sc2[fn][fm], kf[fn], qf[fm][kb]);
        }
        asm volatile("s_nop 7\n\ts_nop 7");

        #pragma unroll
        for (int fm = 0; fm < 2; ++fm) {
            float pm = sc2[0][fm][0];
            #pragma unroll
            for (int fn = 0; fn < 4; ++fn)
                #pragma unroll
                for (int r = 0; r < 4; ++r)
                    if (fn | r) pm = fmaxf(pm, sc2[fn][fm][r]);
            pm = fmaxf(pm, __shfl_xor(pm, 16));
            pm = fmaxf(pm, __shfl_xor(pm, 32));

            float mo = mrow[fm];
            float mn = mo;
            float al = 1.0f;
            if (!__all(pm <= mo + 8.0f)) {
                mn = fmaxf(mo, pm);
                al = exp2_hw(mo - mn);
                mrow[fm] = mn;
                #pragma unroll
                for (int r = 0; r < 4; ++r) {
                    float alr = __shfl(al, albase + r);
                    #pragma unroll
                    for (int fn = 0; fn < 4; ++fn) oacc[fm][fn][r] *= alr;
                }
            }

            float p[4][4];
            float ps = 0.0f;
            #pragma unroll
            for (int fn = 0; fn < 4; ++fn)
                #pragma unroll
                for (int r = 0; r < 4; ++r) {
                    p[fn][r] = exp2_hw(sc2[fn][fm][r] - mn);
                    ps += p[fn][r];
                }
            ps += __shfl_xor(ps, 16);
            ps += __shfl_xor(ps, 32);
            lrs[fm] = lrs[fm] * al + ps;

            int pr = fm * 16 + lr;
            int swz = (pr & 7) << 3;
            #pragma unroll
            for (int fn = 0; fn < 4; ++fn) {
                uint2v w;
                w.x = cvt_pk_bf16(p[fn][0], p[fn][1]);
                w.y = cvt_pk_bf16(p[fn][2], p[fn][3]);
                *(uint2v*)(Pw + ((pr * 64 + fn * 16 + lg * 4) ^ swz)) = w;
            }
        }

        #pragma unroll
        for (int kb = 0; kb < 2; ++kb) {
            short8 pa[2], vf[4];
            #pragma unroll
            for (int fm = 0; fm < 2; ++fm) {
                int pr = fm * 16 + lr;
                pa[fm] = *(const short8*)(Pw + pr * 64 + (((kb * 4 + lg) ^ (pr & 7)) << 3));
            }
            #pragma unroll
            for (int fn = 0; fn < 4; ++fn) {
                int vr = fn * 16 + lr;
                vf[fn] = *(const short8*)(lV + vr * 64 + (((kb * 4 + lg) ^ (vr & 7)) << 3));
            }
            #pragma unroll
            for (int fm = 0; fm < 2; ++fm)
                #pragma unroll
                for (int fn = 0; fn < 4; ++fn)
                    MFMA(oacc[fm][fn], pa[fm], vf[fn]);
        }
        __syncthreads();
    }
    asm volatile("s_nop 7\n\ts_nop 7");

    #pragma unroll
    for (int fm = 0; fm < 2; ++fm)
        #pragma unroll
        for (int r = 0; r < 4; ++r) {
            float linv = __shfl(lrs[fm], albase + r);
            float inv = 1.0f / linv;
            #pragma unroll
            for (int fn = 0; fn < 4; ++fn) {
                size_t off = (size_t)(b * 2048 + q0 + fm * 16 + lg * 4 + r) * 1024 + h * 64 + fn * 16 + lr;
                O[off] = f2bf(oacc[fm][fn][r] * inv);
            }
        }
}

// ---------------- launch ----------------
extern "C" void kernel_launch(void* const* d_in, const int* in_sizes, int n_in,
                              void* d_out, int out_size, void* d_ws, size_t ws_size,
                              hipStream_t stream) {
    const float* x   = (const float*)d_in[0];
    const float* ctx = (const float*)d_in[1];
    const float* Wq  = (const float*)d_in[2];
    const float* Wk  = (const float*)d_in[3];
    const float* Wv  = (const float*)d_in[4];
    const float* Wo  = (const float*)d_in[5];
    const float* W1  = (const float*)d_in[6];
    const float* W2  = (const float*)d_in[7];
    const float* g1  = (const float*)d_in[8];
    const float* b1  = (const float*)d_in[9];
    const float* gc  = (const float*)d_in[10];
    const float* bc  = (const float*)d_in[11];
    const float* g2  = (const float*)d_in[12];
    const float* b2  = (const float*)d_in[13];

    char* ws = (char*)d_ws;
    const size_t OFF_W  = 0;
    const size_t OFF_XN = 25165824;
    const size_t OFF_CN = OFF_XN + 16777216;
    const size_t OFF_QB = OFF_CN + 16777216;
    const size_t OFF_KB = OFF_QB + 16777216;
    const size_t OFF_VT = OFF_KB + 16777216;
    const size_t OFF_X2 = OFF_VT + 16777216;
    const size_t OFF_F1 = OFF_X2 + 33554432;

    short* Wb = (short*)(ws + OFF_W);
    short* XN = (short*)(ws + OFF_XN);
    short* CN = (short*)(ws + OFF_CN);
    short* QB = (short*)(ws + OFF_QB);
    short* KB = (short*)(ws + OFF_KB);
    short* VT = (short*)(ws + OFF_VT);
    float* X2 = (float*)(ws + OFF_X2);
    short* F1 = (short*)(ws + OFF_F1);
    short* OB = XN;                       // xn dead after Q projection
    short* H  = CN;                       // cn dead after K/V projections
    float* P2 = (float*)(ws + OFF_QB);    // QB+KB dead after attn -> 32MB fp32 partial

    const size_t WQo = 0, WKo = 1048576, WVo = 2097152, WOo = 3145728;
    const size_t W1o = 4194304, W2o = 8388608;
    const float QSCALE = 0.125f * 1.4426950408889634f;

    cvt_weights<<<12288, 256, 0, stream>>>(Wq, Wk, Wv, Wo, W1, W2, Wb);
    ln_bf16<<<8192, 256, 0, stream>>>(x, g1, b1, XN);
    ln_bf16<<<8192, 256, 0, stream>>>(ctx, gc, bc, CN);
    gemm_qkv<<<384, 512, 0, stream>>>(XN, CN, Wb + WQo, Wb + WKo, Wb + WVo, QB, KB, VT, QSCALE);
    attn<<<1024, 256, 0, stream>>>(QB, KB, VT, OB);
    gemm_std<1><<<128, 512, 0, stream>>>(OB, Wb + WOo, X2, x, 1024, 1024, 1.0f);
    ln_bf16<<<8192, 256, 0, stream>>>(X2, g2, b2, H);
    gemm_std<2><<<512, 512, 0, stream>>>(H, Wb + W1o, F1, nullptr, 4096, 1024, 1.0f);
    gemm_ff2<<<256, 512, 0, stream>>>(F1, Wb + W2o, (float*)d_out, P2, X2);
    add_f32<<<2048, 256, 0, stream>>>((float*)d_out, P2, 2097152);
}

// Round 5
// 469.067 us; speedup vs baseline: 1.0456x; 1.0456x over previous
//
#include <hip/hip_runtime.h>
#include <cstdint>
#include <cstddef>

typedef __attribute__((ext_vector_type(8))) short short8;
typedef __attribute__((ext_vector_type(4))) short short4v;
typedef __attribute__((ext_vector_type(4))) float f32x4;
typedef __attribute__((ext_vector_type(2))) unsigned uint2v;

#define DEV static __device__ __forceinline__

DEV short f2bf(float f) {
    unsigned u = __builtin_bit_cast(unsigned, f);
    unsigned r = (u + 0x7fffu + ((u >> 16) & 1u)) >> 16;
    return (short)r;
}

DEV unsigned cvt_pk_bf16(float a, float b) {
    unsigned r;
    asm("v_cvt_pk_bf16_f32 %0, %1, %2" : "=v"(r) : "v"(a), "v"(b));
    return r;
}

DEV float exp2_hw(float x) {
    float r;
    asm("v_exp_f32 %0, %1" : "=v"(r) : "v"(x));
    return r;
}

DEV float rcp_hw(float x) {
    float r;
    asm("v_rcp_f32 %0, %1" : "=v"(r) : "v"(x));
    return r;
}

// exact-enough GELU: tanh form, exp2-based. max abs err ~3e-4.
DEV float gelu_f(float v) {
    float t  = v * (1.0f + 0.044715f * v * v);
    float e  = exp2_hw(fminf(2.3022082f * t, 126.0f));   // e^{2*0.79788456*t}
    return v * e * rcp_hw(e + 1.0f);
}

DEV void gld16(const void* g, void* l) {
    __builtin_amdgcn_global_load_lds((const __attribute__((address_space(1))) void*)g,
                                     (__attribute__((address_space(3))) void*)l, 16, 0, 0);
}

#define MFMA(c, a, b) asm volatile("v_mfma_f32_16x16x32_bf16 %0, %1, %2, %0" : "+v"(c) : "v"(a), "v"(b))
#define BAR() asm volatile("s_barrier" ::: "memory")

// ---------------- weight fp32 -> bf16 convert ----------------
__global__ __launch_bounds__(256) void cvt_weights(
    const float* __restrict__ wq, const float* __restrict__ wk,
    const float* __restrict__ wv, const float* __restrict__ wo,
    const float* __restrict__ w1, const float* __restrict__ w2,
    short* __restrict__ dst) {
    long long gid = (long long)blockIdx.x * 256 + threadIdx.x;
    long long i4 = gid * 4;
    const float* src; long long loc;
    if (i4 < (4LL << 20)) {
        int s = (int)(i4 >> 20);
        src = (s == 0) ? wq : (s == 1) ? wk : (s == 2) ? wv : wo;
        loc = i4 & ((1LL << 20) - 1);
    } else {
        long long r = i4 - (4LL << 20);
        int s = (int)(r >> 22);
        src = s ? w2 : w1;
        loc = r & ((1LL << 22) - 1);
    }
    float4 v = *(const float4*)(src + loc);
    short4v o;
    o.x = f2bf(v.x); o.y = f2bf(v.y); o.z = f2bf(v.z); o.w = f2bf(v.w);
    *(short4v*)(dst + i4) = o;
}

// ---------------- LayerNorm (D=1024), fp32 in -> bf16 out ----------------
__global__ __launch_bounds__(256) void ln_bf16(const float* __restrict__ x,
                                               const float* __restrict__ g,
                                               const float* __restrict__ bt,
                                               short* __restrict__ out) {
    int row = blockIdx.x;
    const float4* xr = (const float4*)(x + (size_t)row * 1024);
    float4 v = xr[threadIdx.x];
    float s  = v.x + v.y + v.z + v.w;
    float s2 = v.x*v.x + v.y*v.y + v.z*v.z + v.w*v.w;
    #pragma unroll
    for (int m = 1; m < 64; m <<= 1) { s += __shfl_xor(s, m); s2 += __shfl_xor(s2, m); }
    __shared__ float red[8];
    int wid = threadIdx.x >> 6;
    if ((threadIdx.x & 63) == 0) { red[wid] = s; red[4 + wid] = s2; }
    __syncthreads();
    s  = red[0] + red[1] + red[2] + red[3];
    s2 = red[4] + red[5] + red[6] + red[7];
    float mu  = s * (1.0f / 1024.0f);
    float var = fmaxf(s2 * (1.0f / 1024.0f) - mu * mu, 0.0f);
    float rs  = rsqrtf(var + 1e-5f);
    float4 gv = ((const float4*)g)[threadIdx.x];
    float4 bv = ((const float4*)bt)[threadIdx.x];
    short4v o;
    o.x = f2bf((v.x - mu) * rs * gv.x + bv.x);
    o.y = f2bf((v.y - mu) * rs * gv.y + bv.y);
    o.z = f2bf((v.z - mu) * rs * gv.z + bv.z);
    o.w = f2bf((v.w - mu) * rs * gv.w + bv.w);
    *(short4v*)(out + (size_t)row * 1024 + (size_t)threadIdx.x * 4) = o;
}

// ================= 256x256 8-wave phased GEMM core (unchanged from R4) =================
template<int MODE>
DEV void gemm_core(const short* __restrict__ A, const short* __restrict__ B,
                   void* __restrict__ out, const float* __restrict__ resid,
                   int N, int K, int lda, int ldb, float osc, int bm, int bn) {
    __shared__ short lds[2 * 32768];
    const int tid = threadIdx.x;
    const int row0 = bm << 8, col0 = bn << 8;
    const int wid = tid >> 6, lane = tid & 63;
    const int wm = wid >> 2, wn = wid & 3;
    const int lr = lane & 15, lg = lane >> 4;
    const int NK = K >> 6;

    auto stage = [&](int kt, int which) {
        int d = kt & 1;
        const short* src; int rb; int ld;
        if (which < 2) { src = A; rb = row0; ld = lda; } else { src = B; rb = col0; ld = ldb; }
        int rhalf = (which & 1) << 7;
        short* dst = lds + d * 32768 + which * 8192;
        #pragma unroll
        for (int l = 0; l < 2; ++l) {
            int g = l * 512 + tid;
            int r = g >> 3, c = g & 7;
            gld16(src + (size_t)(rb + rhalf + r) * ld + kt * 64 + ((c ^ (r & 7)) << 3),
                  dst + g * 8);
        }
    };

    f32x4 acc[8][4] = {};

    stage(0, 0); stage(0, 1); stage(0, 2); stage(0, 3);
    if (NK > 1) {
        stage(1, 2); stage(1, 3);
        asm volatile("s_waitcnt vmcnt(4)" ::: "memory");
    } else {
        asm volatile("s_waitcnt vmcnt(0)" ::: "memory");
    }
    BAR();

    const int rBbase = (wn & 1) << 6;
    for (int t = 0; t < NK; ++t) {
        const short* bufA = lds + (t & 1) * 32768 + wm * 8192;
        const short* bufB = lds + (t & 1) * 32768 + 16384 + (wn >> 1) * 8192;
        bool st1 = (t + 1) < NK, st2 = (t + 2) < NK;
        short8 bf2[2][4];

        {
            short8 af[4];
            #pragma unroll
            for (int i = 0; i < 4; ++i) {
                int r = i * 16 + lr;
                af[i] = *(const short8*)(bufA + r * 64 + ((lg ^ (r & 7)) << 3));
            }
            #pragma unroll
            for (int j = 0; j < 4; ++j) {
                int rB = rBbase + j * 16 + lr;
                bf2[0][j] = *(const short8*)(bufB + rB * 64 + ((lg ^ (rB & 7)) << 3));
            }
            if (st1) stage(t + 1, 0);
            BAR();
            __builtin_amdgcn_s_setprio(1);
            #pragma unroll
            for (int i = 0; i < 4; ++i)
                #pragma unroll
                for (int j = 0; j < 4; ++j)
                    MFMA(acc[i][j], af[i], bf2[0][j]);
            __builtin_amdgcn_s_setprio(0);
            BAR();
        }
        {
            short8 af[4];
            #pragma unroll
            for (int i = 0; i < 4; ++i) {
                int r = i * 16 + lr;
                af[i] = *(const short8*)(bufA + r * 64 + (((4 + lg) ^ (r & 7)) << 3));
            }
            #pragma unroll
            for (int j = 0; j < 4; ++j) {
                int rB = rBbase + j * 16 + lr;
                bf2[1][j] = *(const short8*)(bufB + rB * 64 + (((4 + lg) ^ (rB & 7)) << 3));
            }
            if (st1) stage(t + 1, 1);
            BAR();
            __builtin_amdgcn_s_setprio(1);
            #pragma unroll
            for (int i = 0; i < 4; ++i)
                #pragma unroll
                for (int j = 0; j < 4; ++j)
                    MFMA(acc[i][j], af[i], bf2[1][j]);
            __builtin_amdgcn_s_setprio(0);
            BAR();
        }
        {
            short8 af[4];
            #pragma unroll
            for (int i = 0; i < 4; ++i) {
                int r = 64 + i * 16 + lr;
                af[i] = *(const short8*)(bufA + r * 64 + ((lg ^ (r & 7)) << 3));
            }
            if (st2) stage(t + 2, 2);
            BAR();
            __builtin_amdgcn_s_setprio(1);
            #pragma unroll
            for (int i = 0; i < 4; ++i)
                #pragma unroll
                for (int j = 0; j < 4; ++j)
                    MFMA(acc[4 + i][j], af[i], bf2[0][j]);
            __builtin_amdgcn_s_setprio(0);
            BAR();
        }
        {
            short8 af[4];
            #pragma unroll
            for (int i = 0; i < 4; ++i) {
                int r = 64 + i * 16 + lr;
                af[i] = *(const short8*)(bufA + r * 64 + (((4 + lg) ^ (r & 7)) << 3));
            }
            if (st2) stage(t + 2, 3);
            BAR();
            __builtin_amdgcn_s_setprio(1);
            #pragma unroll
            for (int i = 0; i < 4; ++i)
                #pragma unroll
                for (int j = 0; j < 4; ++j)
                    MFMA(acc[4 + i][j], af[i], bf2[1][j]);
            __builtin_amdgcn_s_setprio(0);
            if (st2)      asm volatile("s_waitcnt vmcnt(4)" ::: "memory");
            else if (st1) asm volatile("s_waitcnt vmcnt(0)" ::: "memory");
            BAR();
        }
    }
    asm volatile("s_nop 7\n\ts_nop 7");

    int orow0 = row0 + wm * 128, ocol0 = col0 + wn * 64;
    #pragma unroll
    for (int i = 0; i < 8; ++i)
        #pragma unroll
        for (int j = 0; j < 4; ++j)
            #pragma unroll
            for (int r = 0; r < 4; ++r) {
                int gr = orow0 + i * 16 + lg * 4 + r;
                int gc = ocol0 + j * 16 + lr;
                size_t off = (size_t)gr * N + gc;
                float v = acc[i][j][r];
                if constexpr (MODE == 1) {
                    ((float*)out)[off] = resid ? v + resid[off] : v;
                } else if constexpr (MODE == 2) {
                    ((short*)out)[off] = f2bf(gelu_f(v));
                } else {
                    ((short*)out)[off] = f2bf(v * osc);
                }
            }
}

__global__ __launch_bounds__(512, 2) void gemm_qkv(
    const short* __restrict__ XN, const short* __restrict__ CN,
    const short* __restrict__ Wq, const short* __restrict__ Wk, const short* __restrict__ Wv,
    short* __restrict__ QB, short* __restrict__ KB, short* __restrict__ VT, float qscale) {
    int sid = (blockIdx.x & 7) * 48 + (blockIdx.x >> 3);
    int sub = sid >> 7, i = sid & 127;
    const short *A, *B; short* o; float osc; int N, bm, bn;
    if (sub == 0)      { A = XN; B = Wq; o = QB; osc = qscale; N = 1024; bm = i >> 2; bn = i & 3; }
    else if (sub == 1) { A = CN; B = Wk; o = KB; osc = 1.0f;   N = 1024; bm = i >> 2; bn = i & 3; }
    else               { A = Wv; B = CN; o = VT; osc = 1.0f;   N = 8192; bm = i >> 5; bn = i & 31; }
    gemm_core<3>(A, B, o, nullptr, N, 1024, 1024, 1024, osc, bm, bn);
}

template<int MODE>
__global__ __launch_bounds__(512, 2) void gemm_std(const short* __restrict__ A,
                                                   const short* __restrict__ B,
                                                   void* __restrict__ out,
                                                   const float* __restrict__ resid,
                                                   int N, int K, float osc) {
    int cpx = gridDim.x >> 3;
    int sid = (blockIdx.x & 7) * cpx + (blockIdx.x >> 3);
    int nbn = N >> 8;
    int bm = sid / nbn, bn = sid % nbn;
    gemm_core<MODE>(A, B, out, resid, N, K, K, K, osc, bm, bn);
}

__global__ __launch_bounds__(512, 2) void gemm_ff2(const short* __restrict__ F1,
                                                   const short* __restrict__ W2,
                                                   float* __restrict__ dOut,
                                                   float* __restrict__ P2,
                                                   const float* __restrict__ X2) {
    int sid = (blockIdx.x & 7) * 32 + (blockIdx.x >> 3);
    int h = sid >> 7, i = sid & 127;
    int bm = i >> 2, bn = i & 3;
    const short* A = F1 + h * 2048;
    const short* B = W2 + h * 2048;
    float* o = h ? P2 : dOut;
    const float* r = h ? nullptr : X2;
    gemm_core<1>(A, B, o, r, 1024, 2048, 4096, 4096, 1.0f, bm, bn);
}

__global__ __launch_bounds__(256) void add_f32(float* __restrict__ dst,
                                               const float* __restrict__ src, int n4) {
    int i = blockIdx.x * 256 + threadIdx.x;
    int stride = gridDim.x * 256;
    for (; i < n4; i += stride) {
        float4 a = ((const float4*)dst)[i];
        float4 b = ((const float4*)src)[i];
        a.x += b.x; a.y += b.y; a.z += b.z; a.w += b.w;
        ((float4*)dst)[i] = a;
    }
}

// ---------------- Flash attention v2: 8 waves, 256 q-rows, double-buffered K/V ----------------
// grid = 512 blocks (B*H=64 x 8 q-tiles), XCD-chunked so each bh's 8 blocks share an XCD L2.
__global__ __launch_bounds__(512) void attn(const short* __restrict__ Q,
                                            const short* __restrict__ K,
                                            const short* __restrict__ Vt,
                                            short* __restrict__ O) {
    __shared__ short lK[2][64 * 64];
    __shared__ short lV[2][64 * 64];
    __shared__ short lP[8][32 * 64];
    int tid = threadIdx.x;
    int sid = (blockIdx.x & 7) * 64 + (blockIdx.x >> 3);
    int bh = sid >> 3, qt = sid & 7;
    int b = bh >> 4, h = bh & 15;
    int wid = tid >> 6, lane = tid & 63;
    int lr = lane & 15, lg = lane >> 4;
    int q0 = qt * 256 + wid * 32;

    short8 qf[2][2];
    #pragma unroll
    for (int fm = 0; fm < 2; ++fm)
        #pragma unroll
        for (int kb = 0; kb < 2; ++kb) {
            size_t roff = (size_t)(b * 2048 + q0 + fm * 16 + lr) * 1024 + h * 64 + kb * 32 + lg * 8;
            qf[fm][kb] = *(const short8*)(Q + roff);
        }

    f32x4 oacc[2][4] = {};
    float mrow[2] = { -1e30f, -1e30f };
    float lrs[2]  = { 0.0f, 0.0f };

    const short* Kb = K + (size_t)(b * 2048) * 1024 + h * 64;
    const short* Vb = Vt + (size_t)(h * 64) * 8192 + b * 2048;
    short* Pw = lP[wid];
    int albase = (lane & 48) >> 2;

    // one K-row load + one V-row load per thread per step (512 thr x 16B = 8KB each)
    int sr = tid >> 3, sc = tid & 7;
    int ssl = sc ^ (sr & 7);
    auto stage = [&](int st, int d) {
        gld16(Kb + (size_t)(st * 64 + sr) * 1024 + ssl * 8, &lK[d][tid * 8]);
        gld16(Vb + (size_t)sr * 8192 + st * 64 + ssl * 8, &lV[d][tid * 8]);
    };

    stage(0, 0);
    asm volatile("s_waitcnt vmcnt(0)" ::: "memory");
    BAR();

    for (int st = 0; st < 32; ++st) {
        int d = st & 1;
        if (st + 1 < 32) stage(st + 1, d ^ 1);   // issue-early: lands during compute

        f32x4 sc2[4][2] = {};
        #pragma unroll
        for (int kb = 0; kb < 2; ++kb) {
            short8 kf[4];
            #pragma unroll
            for (int fn = 0; fn < 4; ++fn) {
                int kr = fn * 16 + lr;
                kf[fn] = *(const short8*)(lK[d] + kr * 64 + (((kb * 4 + lg) ^ (kr & 7)) << 3));
            }
            #pragma unroll
            for (int fn = 0; fn < 4; ++fn)
                #pragma unroll
                for (int fm = 0; fm < 2; ++fm)
                    MFMA(sc2[fn][fm], kf[fn], qf[fm][kb]);
        }
        asm volatile("s_nop 7\n\ts_nop 7");

        #pragma unroll
        for (int fm = 0; fm < 2; ++fm) {
            float pm = sc2[0][fm][0];
            #pragma unroll
            for (int fn = 0; fn < 4; ++fn)
                #pragma unroll
                for (int r = 0; r < 4; ++r)
                    if (fn | r) pm = fmaxf(pm, sc2[fn][fm][r]);
            pm = fmaxf(pm, __shfl_xor(pm, 16));
            pm = fmaxf(pm, __shfl_xor(pm, 32));

            float mo = mrow[fm];
            float mn = mo;
            float al = 1.0f;
            if (!__all(pm <= mo + 8.0f)) {
                mn = fmaxf(mo, pm);
                al = exp2_hw(mo - mn);
                mrow[fm] = mn;
                #pragma unroll
                for (int r = 0; r < 4; ++r) {
                    float alr = __shfl(al, albase + r);
                    #pragma unroll
                    for (int fn = 0; fn < 4; ++fn) oacc[fm][fn][r] *= alr;
                }
            }

            float p[4][4];
            float ps = 0.0f;
            #pragma unroll
            for (int fn = 0; fn < 4; ++fn)
                #pragma unroll
                for (int r = 0; r < 4; ++r) {
                    p[fn][r] = exp2_hw(sc2[fn][fm][r] - mn);
                    ps += p[fn][r];
                }
            ps += __shfl_xor(ps, 16);
            ps += __shfl_xor(ps, 32);
            lrs[fm] = lrs[fm] * al + ps;

            int pr = fm * 16 + lr;
            int swz = (pr & 7) << 3;
            #pragma unroll
            for (int fn = 0; fn < 4; ++fn) {
                uint2v w;
                w.x = cvt_pk_bf16(p[fn][0], p[fn][1]);
                w.y = cvt_pk_bf16(p[fn][2], p[fn][3]);
                *(uint2v*)(Pw + ((pr * 64 + fn * 16 + lg * 4) ^ swz)) = w;
            }
        }

        #pragma unroll
        for (int kb = 0; kb < 2; ++kb) {
            short8 pa[2], vf[4];
            #pragma unroll
            for (int fm = 0; fm < 2; ++fm) {
                int pr = fm * 16 + lr;
                pa[fm] = *(const short8*)(Pw + pr * 64 + (((kb * 4 + lg) ^ (pr & 7)) << 3));
            }
            #pragma unroll
            for (int fn = 0; fn < 4; ++fn) {
                int vr = fn * 16 + lr;
                vf[fn] = *(const short8*)(lV[d] + vr * 64 + (((kb * 4 + lg) ^ (vr & 7)) << 3));
            }
            #pragma unroll
            for (int fm = 0; fm < 2; ++fm)
                #pragma unroll
                for (int fn = 0; fn < 4; ++fn)
                    MFMA(oacc[fm][fn], pa[fm], vf[fn]);
        }

        // next buffer's loads have had the whole compute phase to land
        asm volatile("s_waitcnt vmcnt(0)" ::: "memory");
        BAR();
    }
    asm volatile("s_nop 7\n\ts_nop 7");

    #pragma unroll
    for (int fm = 0; fm < 2; ++fm)
        #pragma unroll
        for (int r = 0; r < 4; ++r) {
            float linv = __shfl(lrs[fm], albase + r);
            float inv = 1.0f / linv;
            #pragma unroll
            for (int fn = 0; fn < 4; ++fn) {
                size_t off = (size_t)(b * 2048 + q0 + fm * 16 + lg * 4 + r) * 1024 + h * 64 + fn * 16 + lr;
                O[off] = f2bf(oacc[fm][fn][r] * inv);
            }
        }
}

// ---------------- launch ----------------
extern "C" void kernel_launch(void* const* d_in, const int* in_sizes, int n_in,
                              void* d_out, int out_size, void* d_ws, size_t ws_size,
                              hipStream_t stream) {
    const float* x   = (const float*)d_in[0];
    const float* ctx = (const float*)d_in[1];
    const float* Wq  = (const float*)d_in[2];
    const float* Wk  = (const float*)d_in[3];
    const float* Wv  = (const float*)d_in[4];
    const float* Wo  = (const float*)d_in[5];
    const float* W1  = (const float*)d_in[6];
    const float* W2  = (const float*)d_in[7];
    const float* g1  = (const float*)d_in[8];
    const float* b1  = (const float*)d_in[9];
    const float* gc  = (const float*)d_in[10];
    const float* bc  = (const float*)d_in[11];
    const float* g2  = (const float*)d_in[12];
    const float* b2  = (const float*)d_in[13];

    char* ws = (char*)d_ws;
    const size_t OFF_W  = 0;
    const size_t OFF_XN = 25165824;
    const size_t OFF_CN = OFF_XN + 16777216;
    const size_t OFF_QB = OFF_CN + 16777216;
    const size_t OFF_KB = OFF_QB + 16777216;
    const size_t OFF_VT = OFF_KB + 16777216;
    const size_t OFF_X2 = OFF_VT + 16777216;
    const size_t OFF_F1 = OFF_X2 + 33554432;

    short* Wb = (short*)(ws + OFF_W);
    short* XN = (short*)(ws + OFF_XN);
    short* CN = (short*)(ws + OFF_CN);
    short* QB = (short*)(ws + OFF_QB);
    short* KB = (short*)(ws + OFF_KB);
    short* VT = (short*)(ws + OFF_VT);
    float* X2 = (float*)(ws + OFF_X2);
    short* F1 = (short*)(ws + OFF_F1);
    short* OB = XN;
    short* H  = CN;
    float* P2 = (float*)(ws + OFF_QB);

    const size_t WQo = 0, WKo = 1048576, WVo = 2097152, WOo = 3145728;
    const size_t W1o = 4194304, W2o = 8388608;
    const float QSCALE = 0.125f * 1.4426950408889634f;

    cvt_weights<<<12288, 256, 0, stream>>>(Wq, Wk, Wv, Wo, W1, W2, Wb);
    ln_bf16<<<8192, 256, 0, stream>>>(x, g1, b1, XN);
    ln_bf16<<<8192, 256, 0, stream>>>(ctx, gc, bc, CN);
    gemm_qkv<<<384, 512, 0, stream>>>(XN, CN, Wb + WQo, Wb + WKo, Wb + WVo, QB, KB, VT, QSCALE);
    attn<<<512, 512, 0, stream>>>(QB, KB, VT, OB);
    gemm_std<1><<<128, 512, 0, stream>>>(OB, Wb + WOo, X2, x, 1024, 1024, 1.0f);
    ln_bf16<<<8192, 256, 0, stream>>>(X2, g2, b2, H);
    gemm_std<2><<<512, 512, 0, stream>>>(H, Wb + W1o, F1, nullptr, 4096, 1024, 1.0f);
    gemm_ff2<<<256, 512, 0, stream>>>(F1, Wb + W2o, (float*)d_out, P2, X2);
    add_f32<<<2048, 256, 0, stream>>>((float*)d_out, P2, 2097152);
}

// Round 10
// 467.413 us; speedup vs baseline: 1.0493x; 1.0035x over previous
//
#include <hip/hip_runtime.h>
#include <cstdint>
#include <cstddef>

typedef __attribute__((ext_vector_type(8))) short short8;
typedef __attribute__((ext_vector_type(4))) short short4v;
typedef __attribute__((ext_vector_type(4))) float f32x4;
typedef __attribute__((ext_vector_type(4))) unsigned uint4v;

#define DEV static __device__ __forceinline__

DEV short f2bf(float f) {
    unsigned u = __builtin_bit_cast(unsigned, f);
    unsigned r = (u + 0x7fffu + ((u >> 16) & 1u)) >> 16;
    return (short)r;
}

DEV unsigned cvt_pk_bf16(float a, float b) {
    unsigned r;
    asm("v_cvt_pk_bf16_f32 %0, %1, %2" : "=v"(r) : "v"(a), "v"(b));
    return r;
}

DEV float exp2_hw(float x) {
    float r;
    asm("v_exp_f32 %0, %1" : "=v"(r) : "v"(x));
    return r;
}

DEV float rcp_hw(float x) {
    float r;
    asm("v_rcp_f32 %0, %1" : "=v"(r) : "v"(x));
    return r;
}

// exact-enough GELU: tanh form, exp2-based. max abs err ~3e-4.
DEV float gelu_f(float v) {
    float t  = v * (1.0f + 0.044715f * v * v);
    float e  = exp2_hw(fminf(2.3022082f * t, 126.0f));
    return v * e * rcp_hw(e + 1.0f);
}

DEV void gld16(const void* g, void* l) {
    __builtin_amdgcn_global_load_lds((const __attribute__((address_space(1))) void*)g,
                                     (__attribute__((address_space(3))) void*)l, 16, 0, 0);
}

#define MFMA(c, a, b) asm volatile("v_mfma_f32_16x16x32_bf16 %0, %1, %2, %0" : "+v"(c) : "v"(a), "v"(b))
#define BAR() asm volatile("s_barrier" ::: "memory")

// ---------------- weight fp32 -> bf16 convert ----------------
__global__ __launch_bounds__(256) void cvt_weights(
    const float* __restrict__ wq, const float* __restrict__ wk,
    const float* __restrict__ wv, const float* __restrict__ wo,
    const float* __restrict__ w1, const float* __restrict__ w2,
    short* __restrict__ dst) {
    long long gid = (long long)blockIdx.x * 256 + threadIdx.x;
    long long i4 = gid * 4;
    const float* src; long long loc;
    if (i4 < (4LL << 20)) {
        int s = (int)(i4 >> 20);
        src = (s == 0) ? wq : (s == 1) ? wk : (s == 2) ? wv : wo;
        loc = i4 & ((1LL << 20) - 1);
    } else {
        long long r = i4 - (4LL << 20);
        int s = (int)(r >> 22);
        src = s ? w2 : w1;
        loc = r & ((1LL << 22) - 1);
    }
    float4 v = *(const float4*)(src + loc);
    short4v o;
    o.x = f2bf(v.x); o.y = f2bf(v.y); o.z = f2bf(v.z); o.w = f2bf(v.w);
    *(short4v*)(dst + i4) = o;
}

// ---------------- LayerNorm (D=1024), fp32 in -> bf16 out ----------------
__global__ __launch_bounds__(256) void ln_bf16(const float* __restrict__ x,
                                               const float* __restrict__ g,
                                               const float* __restrict__ bt,
                                               short* __restrict__ out) {
    int row = blockIdx.x;
    const float4* xr = (const float4*)(x + (size_t)row * 1024);
    float4 v = xr[threadIdx.x];
    float s  = v.x + v.y + v.z + v.w;
    float s2 = v.x*v.x + v.y*v.y + v.z*v.z + v.w*v.w;
    #pragma unroll
    for (int m = 1; m < 64; m <<= 1) { s += __shfl_xor(s, m); s2 += __shfl_xor(s2, m); }
    __shared__ float red[8];
    int wid = threadIdx.x >> 6;
    if ((threadIdx.x & 63) == 0) { red[wid] = s; red[4 + wid] = s2; }
    __syncthreads();
    s  = red[0] + red[1] + red[2] + red[3];
    s2 = red[4] + red[5] + red[6] + red[7];
    float mu  = s * (1.0f / 1024.0f);
    float var = fmaxf(s2 * (1.0f / 1024.0f) - mu * mu, 0.0f);
    float rs  = rsqrtf(var + 1e-5f);
    float4 gv = ((const float4*)g)[threadIdx.x];
    float4 bv = ((const float4*)bt)[threadIdx.x];
    short4v o;
    o.x = f2bf((v.x - mu) * rs * gv.x + bv.x);
    o.y = f2bf((v.y - mu) * rs * gv.y + bv.y);
    o.z = f2bf((v.z - mu) * rs * gv.z + bv.z);
    o.w = f2bf((v.w - mu) * rs * gv.w + bv.w);
    *(short4v*)(out + (size_t)row * 1024 + (size_t)threadIdx.x * 4) = o;
}

// ================= 256x256 8-wave phased GEMM core (unchanged) =================
template<int MODE>
DEV void gemm_core(const short* __restrict__ A, const short* __restrict__ B,
                   void* __restrict__ out, const float* __restrict__ resid,
                   int N, int K, int lda, int ldb, float osc, int bm, int bn) {
    __shared__ short lds[2 * 32768];
    const int tid = threadIdx.x;
    const int row0 = bm << 8, col0 = bn << 8;
    const int wid = tid >> 6, lane = tid & 63;
    const int wm = wid >> 2, wn = wid & 3;
    const int lr = lane & 15, lg = lane >> 4;
    const int NK = K >> 6;

    auto stage = [&](int kt, int which) {
        int d = kt & 1;
        const short* src; int rb; int ld;
        if (which < 2) { src = A; rb = row0; ld = lda; } else { src = B; rb = col0; ld = ldb; }
        int rhalf = (which & 1) << 7;
        short* dst = lds + d * 32768 + which * 8192;
        #pragma unroll
        for (int l = 0; l < 2; ++l) {
            int g = l * 512 + tid;
            int r = g >> 3, c = g & 7;
            gld16(src + (size_t)(rb + rhalf + r) * ld + kt * 64 + ((c ^ (r & 7)) << 3),
                  dst + g * 8);
        }
    };

    f32x4 acc[8][4] = {};

    stage(0, 0); stage(0, 1); stage(0, 2); stage(0, 3);
    if (NK > 1) {
        stage(1, 2); stage(1, 3);
        asm volatile("s_waitcnt vmcnt(4)" ::: "memory");
    } else {
        asm volatile("s_waitcnt vmcnt(0)" ::: "memory");
    }
    BAR();

    const int rBbase = (wn & 1) << 6;
    for (int t = 0; t < NK; ++t) {
        const short* bufA = lds + (t & 1) * 32768 + wm * 8192;
        const short* bufB = lds + (t & 1) * 32768 + 16384 + (wn >> 1) * 8192;
        bool st1 = (t + 1) < NK, st2 = (t + 2) < NK;
        short8 bf2[2][4];

        {
            short8 af[4];
            #pragma unroll
            for (int i = 0; i < 4; ++i) {
                int r = i * 16 + lr;
                af[i] = *(const short8*)(bufA + r * 64 + ((lg ^ (r & 7)) << 3));
            }
            #pragma unroll
            for (int j = 0; j < 4; ++j) {
                int rB = rBbase + j * 16 + lr;
                bf2[0][j] = *(const short8*)(bufB + rB * 64 + ((lg ^ (rB & 7)) << 3));
            }
            if (st1) stage(t + 1, 0);
            BAR();
            __builtin_amdgcn_s_setprio(1);
            #pragma unroll
            for (int i = 0; i < 4; ++i)
                #pragma unroll
                for (int j = 0; j < 4; ++j)
                    MFMA(acc[i][j], af[i], bf2[0][j]);
            __builtin_amdgcn_s_setprio(0);
            BAR();
        }
        {
            short8 af[4];
            #pragma unroll
            for (int i = 0; i < 4; ++i) {
                int r = i * 16 + lr;
                af[i] = *(const short8*)(bufA + r * 64 + (((4 + lg) ^ (r & 7)) << 3));
            }
            #pragma unroll
            for (int j = 0; j < 4; ++j) {
                int rB = rBbase + j * 16 + lr;
                bf2[1][j] = *(const short8*)(bufB + rB * 64 + (((4 + lg) ^ (rB & 7)) << 3));
            }
            if (st1) stage(t + 1, 1);
            BAR();
            __builtin_amdgcn_s_setprio(1);
            #pragma unroll
            for (int i = 0; i < 4; ++i)
                #pragma unroll
                for (int j = 0; j < 4; ++j)
                    MFMA(acc[i][j], af[i], bf2[1][j]);
            __builtin_amdgcn_s_setprio(0);
            BAR();
        }
        {
            short8 af[4];
            #pragma unroll
            for (int i = 0; i < 4; ++i) {
                int r = 64 + i * 16 + lr;
                af[i] = *(const short8*)(bufA + r * 64 + ((lg ^ (r & 7)) << 3));
            }
            if (st2) stage(t + 2, 2);
            BAR();
            __builtin_amdgcn_s_setprio(1);
            #pragma unroll
            for (int i = 0; i < 4; ++i)
                #pragma unroll
                for (int j = 0; j < 4; ++j)
                    MFMA(acc[4 + i][j], af[i], bf2[0][j]);
            __builtin_amdgcn_s_setprio(0);
            BAR();
        }
        {
            short8 af[4];
            #pragma unroll
            for (int i = 0; i < 4; ++i) {
                int r = 64 + i * 16 + lr;
                af[i] = *(const short8*)(bufA + r * 64 + (((4 + lg) ^ (r & 7)) << 3));
            }
            if (st2) stage(t + 2, 3);
            BAR();
            __builtin_amdgcn_s_setprio(1);
            #pragma unroll
            for (int i = 0; i < 4; ++i)
                #pragma unroll
                for (int j = 0; j < 4; ++j)
                    MFMA(acc[4 + i][j], af[i], bf2[1][j]);
            __builtin_amdgcn_s_setprio(0);
            if (st2)      asm volatile("s_waitcnt vmcnt(4)" ::: "memory");
            else if (st1) asm volatile("s_waitcnt vmcnt(0)" ::: "memory");
            BAR();
        }
    }
    asm volatile("s_nop 7\n\ts_nop 7");

    int orow0 = row0 + wm * 128, ocol0 = col0 + wn * 64;
    #pragma unroll
    for (int i = 0; i < 8; ++i)
        #pragma unroll
        for (int j = 0; j < 4; ++j)
            #pragma unroll
            for (int r = 0; r < 4; ++r) {
                int gr = orow0 + i * 16 + lg * 4 + r;
                int gc = ocol0 + j * 16 + lr;
                size_t off = (size_t)gr * N + gc;
                float v = acc[i][j][r];
                if constexpr (MODE == 1) {
                    ((float*)out)[off] = resid ? v + resid[off] : v;
                } else if constexpr (MODE == 2) {
                    ((short*)out)[off] = f2bf(gelu_f(v));
                } else {
                    ((short*)out)[off] = f2bf(v * osc);
                }
            }
}

__global__ __launch_bounds__(512, 2) void gemm_qkv(
    const short* __restrict__ XN, const short* __restrict__ CN,
    const short* __restrict__ Wq, const short* __restrict__ Wk, const short* __restrict__ Wv,
    short* __restrict__ QB, short* __restrict__ KB, short* __restrict__ VT, float qscale) {
    int sid = (blockIdx.x & 7) * 48 + (blockIdx.x >> 3);
    int sub = sid >> 7, i = sid & 127;
    const short *A, *B; short* o; float osc; int N, bm, bn;
    if (sub == 0)      { A = XN; B = Wq; o = QB; osc = qscale; N = 1024; bm = i >> 2; bn = i & 3; }
    else if (sub == 1) { A = CN; B = Wk; o = KB; osc = 1.0f;   N = 1024; bm = i >> 2; bn = i & 3; }
    else               { A = Wv; B = CN; o = VT; osc = 1.0f;   N = 8192; bm = i >> 5; bn = i & 31; }
    gemm_core<3>(A, B, o, nullptr, N, 1024, 1024, 1024, osc, bm, bn);
}

template<int MODE>
__global__ __launch_bounds__(512, 2) void gemm_std(const short* __restrict__ A,
                                                   const short* __restrict__ B,
                                                   void* __restrict__ out,
                                                   const float* __restrict__ resid,
                                                   int N, int K, float osc) {
    int cpx = gridDim.x >> 3;
    int sid = (blockIdx.x & 7) * cpx + (blockIdx.x >> 3);
    int nbn = N >> 8;
    int bm = sid / nbn, bn = sid % nbn;
    gemm_core<MODE>(A, B, out, resid, N, K, K, K, osc, bm, bn);
}

__global__ __launch_bounds__(512, 2) void gemm_ff2(const short* __restrict__ F1,
                                                   const short* __restrict__ W2,
                                                   float* __restrict__ dOut,
                                                   float* __restrict__ P2,
                                                   const float* __restrict__ X2) {
    int sid = (blockIdx.x & 7) * 32 + (blockIdx.x >> 3);
    int h = sid >> 7, i = sid & 127;
    int bm = i >> 2, bn = i & 3;
    const short* A = F1 + h * 2048;
    const short* B = W2 + h * 2048;
    float* o = h ? P2 : dOut;
    const float* r = h ? nullptr : X2;
    gemm_core<1>(A, B, o, r, 1024, 2048, 4096, 4096, 1.0f, bm, bn);
}

__global__ __launch_bounds__(256) void add_f32(float* __restrict__ dst,
                                               const float* __restrict__ src, int n4) {
    int i = blockIdx.x * 256 + threadIdx.x;
    int stride = gridDim.x * 256;
    for (; i < n4; i += stride) {
        float4 a = ((const float4*)dst)[i];
        float4 b = ((const float4*)src)[i];
        a.x += b.x; a.y += b.y; a.z += b.z; a.w += b.w;
        ((float4*)dst)[i] = a;
    }
}

// ---------------- Flash attention v3b: QBLK=128, in-register P (shfl-exchange) ----------------
// grid = 1024 blocks (64 bh x 16 qt), 8 waves x 16 q-rows. LDS = 32KB (K/V dbuf only).
// Swapped QK^T: lane (lr,lg) holds P[q=lr][k=fn*16+lg*4+r]. PV A-frag target: lane (lr,lg)
// word w = U[kb*2+(lg>>1)][w&1] from source sub-lane slg=(lg&1)*2+(w>>1).
// Exchange via unambiguous shfl_xor(32) then shfl_xor(16) + selects (verified lane-by-lane).
__global__ __launch_bounds__(512, 6) void attn(const short* __restrict__ Q,
                                               const short* __restrict__ K,
                                               const short* __restrict__ Vt,
                                               short* __restrict__ O) {
    __shared__ short lK[2][64 * 64];
    __shared__ short lV[2][64 * 64];
    int tid = threadIdx.x;
    int sid = (blockIdx.x & 7) * 128 + (blockIdx.x >> 3);
    int bh = sid >> 4, qt = sid & 15;
    int b = bh >> 4, h = bh & 15;
    int wid = tid >> 6, lane = tid & 63;
    int lr = lane & 15, lg = lane >> 4;
    int q0 = qt * 128 + wid * 16;
    bool cbit = (lane & 16) != 0;            // lg & 1
    bool hihalf = (lane & 32) != 0;          // lg >= 2

    short8 qf[2];
    #pragma unroll
    for (int kb = 0; kb < 2; ++kb) {
        size_t roff = (size_t)(b * 2048 + q0 + lr) * 1024 + h * 64 + kb * 32 + lg * 8;
        qf[kb] = *(const short8*)(Q + roff);
    }

    f32x4 oacc[4] = {};
    float mrow = -1e30f, lsum = 0.0f;

    const short* Kb = K + (size_t)(b * 2048) * 1024 + h * 64;
    const short* Vb = Vt + (size_t)(h * 64) * 8192 + b * 2048;
    int albase = (lane & 48) >> 2;           // lg*4

    int sr = tid >> 3, scc = tid & 7;
    int ssl = scc ^ (sr & 7);
    auto stage = [&](int st, int d) {
        gld16(Kb + (size_t)(st * 64 + sr) * 1024 + ssl * 8, &lK[d][tid * 8]);
        gld16(Vb + (size_t)sr * 8192 + st * 64 + ssl * 8, &lV[d][tid * 8]);
    };

    stage(0, 0);
    asm volatile("s_waitcnt vmcnt(0)" ::: "memory");
    BAR();

    for (int st = 0; st < 32; ++st) {
        int d = st & 1;
        if (st + 1 < 32) stage(st + 1, d ^ 1);

        // S^T = K * Q^T : sc2[fn], row k = fn*16+lg*4+r, col q = lr
        f32x4 sc2[4] = {};
        #pragma unroll
        for (int kb = 0; kb < 2; ++kb) {
            short8 kf[4];
            #pragma unroll
            for (int fn = 0; fn < 4; ++fn) {
                int kr = fn * 16 + lr;
                kf[fn] = *(const short8*)(lK[d] + kr * 64 + (((kb * 4 + lg) ^ (kr & 7)) << 3));
            }
            #pragma unroll
            for (int fn = 0; fn < 4; ++fn)
                MFMA(sc2[fn], kf[fn], qf[kb]);
        }
        asm volatile("s_nop 7\n\ts_nop 7");

        // softmax (in-lane 16 + 2 shuffles)
        float pm = sc2[0][0];
        #pragma unroll
        for (int fn = 0; fn < 4; ++fn)
            #pragma unroll
            for (int r = 0; r < 4; ++r)
                if (fn | r) pm = fmaxf(pm, sc2[fn][r]);
        pm = fmaxf(pm, __shfl_xor(pm, 16));
        pm = fmaxf(pm, __shfl_xor(pm, 32));

        float al = 1.0f;
        float mn = mrow;
        if (!__all(pm <= mrow + 8.0f)) {
            mn = fmaxf(mrow, pm);
            al = exp2_hw(mrow - mn);
            mrow = mn;
            #pragma unroll
            for (int r = 0; r < 4; ++r) {
                float alr = __shfl(al, albase + r);
                #pragma unroll
                for (int fn = 0; fn < 4; ++fn) oacc[fn][r] *= alr;
            }
        }

        float p[4][4];
        float ps = 0.0f;
        #pragma unroll
        for (int fn = 0; fn < 4; ++fn)
            #pragma unroll
            for (int r = 0; r < 4; ++r) {
                p[fn][r] = exp2_hw(sc2[fn][r] - mn);
                ps += p[fn][r];
            }
        ps += __shfl_xor(ps, 16);
        ps += __shfl_xor(ps, 32);
        lsum = lsum * al + ps;

        // pack P to bf16 pairs: U[fn][w'] covers k = fn*16 + lg*4 + 2w' + {0,1}
        unsigned U[4][2];
        #pragma unroll
        for (int fn = 0; fn < 4; ++fn) {
            U[fn][0] = cvt_pk_bf16(p[fn][0], p[fn][1]);
            U[fn][1] = cvt_pk_bf16(p[fn][2], p[fn][3]);
        }

        // build PV A-frags in-register, then PV MFMAs
        #pragma unroll
        for (int kb = 0; kb < 2; ++kb) {
            unsigned lo0 = U[kb * 2][0],     lo1 = U[kb * 2][1];
            unsigned hi0 = U[kb * 2 + 1][0], hi1 = U[kb * 2 + 1][1];
            // half-exchange: lanes<32 get U_lo from lane+32; lanes>=32 get U_hi from lane-32
            unsigned t0 = (unsigned)__shfl_xor((int)lo0, 32);
            unsigned t1 = (unsigned)__shfl_xor((int)lo1, 32);
            unsigned s0 = (unsigned)__shfl_xor((int)hi0, 32);
            unsigned s1 = (unsigned)__shfl_xor((int)hi1, 32);
            unsigned nlo0 = hihalf ? s0 : lo0;
            unsigned nlo1 = hihalf ? s1 : lo1;
            unsigned nhi0 = hihalf ? hi0 : t0;
            unsigned nhi1 = hihalf ? hi1 : t1;
            // within-half pair exchange + select by cbit (lg&1)
            unsigned a0 = cbit ? nhi0 : nlo0;
            unsigned a1 = cbit ? nhi1 : nlo1;
            unsigned x0 = (unsigned)__shfl_xor((int)nlo0, 16);
            unsigned x1 = (unsigned)__shfl_xor((int)nlo1, 16);
            unsigned y0 = (unsigned)__shfl_xor((int)nhi0, 16);
            unsigned y1 = (unsigned)__shfl_xor((int)nhi1, 16);
            unsigned b0 = cbit ? y0 : x0;
            unsigned b1 = cbit ? y1 : x1;
            uint4v pw;
            pw.x = cbit ? b0 : a0;
            pw.y = cbit ? b1 : a1;
            pw.z = cbit ? a0 : b0;
            pw.w = cbit ? a1 : b1;
            short8 pa = __builtin_bit_cast(short8, pw);

            short8 vf[4];
            #pragma unroll
            for (int fn = 0; fn < 4; ++fn) {
                int vr = fn * 16 + lr;
                vf[fn] = *(const short8*)(lV[d] + vr * 64 + (((kb * 4 + lg) ^ (vr & 7)) << 3));
            }
            #pragma unroll
            for (int fn = 0; fn < 4; ++fn)
                MFMA(oacc[fn], pa, vf[fn]);
        }

        asm volatile("s_waitcnt vmcnt(0)" ::: "memory");
        BAR();
    }
    asm volatile("s_nop 7\n\ts_nop 7");

    #pragma unroll
    for (int r = 0; r < 4; ++r) {
        float linv = __shfl(lsum, albase + r);
        float inv = 1.0f / linv;
        #pragma unroll
        for (int fn = 0; fn < 4; ++fn) {
            size_t off = (size_t)(b * 2048 + q0 + lg * 4 + r) * 1024 + h * 64 + fn * 16 + lr;
            O[off] = f2bf(oacc[fn][r] * inv);
        }
    }
}

// ---------------- launch ----------------
extern "C" void kernel_launch(void* const* d_in, const int* in_sizes, int n_in,
                              void* d_out, int out_size, void* d_ws, size_t ws_size,
                              hipStream_t stream) {
    const float* x   = (const float*)d_in[0];
    const float* ctx = (const float*)d_in[1];
    const float* Wq  = (const float*)d_in[2];
    const float* Wk  = (const float*)d_in[3];
    const float* Wv  = (const float*)d_in[4];
    const float* Wo  = (const float*)d_in[5];
    const float* W1  = (const float*)d_in[6];
    const float* W2  = (const float*)d_in[7];
    const float* g1  = (const float*)d_in[8];
    const float* b1  = (const float*)d_in[9];
    const float* gc  = (const float*)d_in[10];
    const float* bc  = (const float*)d_in[11];
    const float* g2  = (const float*)d_in[12];
    const float* b2  = (const float*)d_in[13];

    char* ws = (char*)d_ws;
    const size_t OFF_W  = 0;
    const size_t OFF_XN = 25165824;
    const size_t OFF_CN = OFF_XN + 16777216;
    const size_t OFF_QB = OFF_CN + 16777216;
    const size_t OFF_KB = OFF_QB + 16777216;
    const size_t OFF_VT = OFF_KB + 16777216;
    const size_t OFF_X2 = OFF_VT + 16777216;
    const size_t OFF_F1 = OFF_X2 + 33554432;

    short* Wb = (short*)(ws + OFF_W);
    short* XN = (short*)(ws + OFF_XN);
    short* CN = (short*)(ws + OFF_CN);
    short* QB = (short*)(ws + OFF_QB);
    short* KB = (short*)(ws + OFF_KB);
    short* VT = (short*)(ws + OFF_VT);
    float* X2 = (float*)(ws + OFF_X2);
    short* F1 = (short*)(ws + OFF_F1);
    short* OB = XN;
    short* H  = CN;
    float* P2 = (float*)(ws + OFF_QB);

    const size_t WQo = 0, WKo = 1048576, WVo = 2097152, WOo = 3145728;
    const size_t W1o = 4194304, W2o = 8388608;
    const float QSCALE = 0.125f * 1.4426950408889634f;

    cvt_weights<<<12288, 256, 0, stream>>>(Wq, Wk, Wv, Wo, W1, W2, Wb);
    ln_bf16<<<8192, 256, 0, stream>>>(x, g1, b1, XN);
    ln_bf16<<<8192, 256, 0, stream>>>(ctx, gc, bc, CN);
    gemm_qkv<<<384, 512, 0, stream>>>(XN, CN, Wb + WQo, Wb + WKo, Wb + WVo, QB, KB, VT, QSCALE);
    attn<<<1024, 512, 0, stream>>>(QB, KB, VT, OB);
    gemm_std<1><<<128, 512, 0, stream>>>(OB, Wb + WOo, X2, x, 1024, 1024, 1.0f);
    ln_bf16<<<8192, 256, 0, stream>>>(X2, g2, b2, H);
    gemm_std<2><<<512, 512, 0, stream>>>(H, Wb + W1o, F1, nullptr, 4096, 1024, 1.0f);
    gemm_ff2<<<256, 512, 0, stream>>>(F1, Wb + W2o, (float*)d_out, P2, X2);
    add_f32<<<2048, 256, 0, stream>>>((float*)d_out, P2, 2097152);
}

// Round 11
// 453.530 us; speedup vs baseline: 1.0814x; 1.0306x over previous
//
#include <hip/hip_runtime.h>
#include <cstdint>
#include <cstddef>

typedef __attribute__((ext_vector_type(8))) short short8;
typedef __attribute__((ext_vector_type(4))) short short4v;
typedef __attribute__((ext_vector_type(4))) float f32x4;
typedef __attribute__((ext_vector_type(4))) unsigned uint4v;

#define DEV static __device__ __forceinline__

DEV short f2bf(float f) {
    unsigned u = __builtin_bit_cast(unsigned, f);
    unsigned r = (u + 0x7fffu + ((u >> 16) & 1u)) >> 16;
    return (short)r;
}

DEV unsigned cvt_pk_bf16(float a, float b) {
    unsigned r;
    asm("v_cvt_pk_bf16_f32 %0, %1, %2" : "=v"(r) : "v"(a), "v"(b));
    return r;
}

DEV float exp2_hw(float x) {
    float r;
    asm("v_exp_f32 %0, %1" : "=v"(r) : "v"(x));
    return r;
}

DEV float rcp_hw(float x) {
    float r;
    asm("v_rcp_f32 %0, %1" : "=v"(r) : "v"(x));
    return r;
}

// exact-enough GELU: tanh form, exp2-based. max abs err ~3e-4.
DEV float gelu_f(float v) {
    float t  = v * (1.0f + 0.044715f * v * v);
    float e  = exp2_hw(fminf(2.3022082f * t, 126.0f));
    return v * e * rcp_hw(e + 1.0f);
}

DEV void gld16(const void* g, void* l) {
    __builtin_amdgcn_global_load_lds((const __attribute__((address_space(1))) void*)g,
                                     (__attribute__((address_space(3))) void*)l, 16, 0, 0);
}

#define MFMA(c, a, b) asm volatile("v_mfma_f32_16x16x32_bf16 %0, %1, %2, %0" : "+v"(c) : "v"(a), "v"(b))
#define BAR() asm volatile("s_barrier" ::: "memory")

// cross-32 reduction helper: v_permlane32_swap_b32 semantics (pinned R9/R10): D.hi <-> S.lo
DEV float red32_max(float v) {
    float a = v, b = v;
    asm volatile("v_permlane32_swap_b32 %0, %1" : "+v"(a), "+v"(b));
    return fmaxf(a, b);
}
DEV float red32_add(float v) {
    float a = v, b = v;
    asm volatile("v_permlane32_swap_b32 %0, %1" : "+v"(a), "+v"(b));
    return a + b;
}

// ---------------- weight fp32 -> bf16 convert ----------------
__global__ __launch_bounds__(256) void cvt_weights(
    const float* __restrict__ wq, const float* __restrict__ wk,
    const float* __restrict__ wv, const float* __restrict__ wo,
    const float* __restrict__ w1, const float* __restrict__ w2,
    short* __restrict__ dst) {
    long long gid = (long long)blockIdx.x * 256 + threadIdx.x;
    long long i4 = gid * 4;
    const float* src; long long loc;
    if (i4 < (4LL << 20)) {
        int s = (int)(i4 >> 20);
        src = (s == 0) ? wq : (s == 1) ? wk : (s == 2) ? wv : wo;
        loc = i4 & ((1LL << 20) - 1);
    } else {
        long long r = i4 - (4LL << 20);
        int s = (int)(r >> 22);
        src = s ? w2 : w1;
        loc = r & ((1LL << 22) - 1);
    }
    float4 v = *(const float4*)(src + loc);
    short4v o;
    o.x = f2bf(v.x); o.y = f2bf(v.y); o.z = f2bf(v.z); o.w = f2bf(v.w);
    *(short4v*)(dst + i4) = o;
}

// ---------------- LayerNorm (D=1024), fp32 in -> bf16 out ----------------
__global__ __launch_bounds__(256) void ln_bf16(const float* __restrict__ x,
                                               const float* __restrict__ g,
                                               const float* __restrict__ bt,
                                               short* __restrict__ out) {
    int row = blockIdx.x;
    const float4* xr = (const float4*)(x + (size_t)row * 1024);
    float4 v = xr[threadIdx.x];
    float s  = v.x + v.y + v.z + v.w;
    float s2 = v.x*v.x + v.y*v.y + v.z*v.z + v.w*v.w;
    #pragma unroll
    for (int m = 1; m < 64; m <<= 1) { s += __shfl_xor(s, m); s2 += __shfl_xor(s2, m); }
    __shared__ float red[8];
    int wid = threadIdx.x >> 6;
    if ((threadIdx.x & 63) == 0) { red[wid] = s; red[4 + wid] = s2; }
    __syncthreads();
    s  = red[0] + red[1] + red[2] + red[3];
    s2 = red[4] + red[5] + red[6] + red[7];
    float mu  = s * (1.0f / 1024.0f);
    float var = fmaxf(s2 * (1.0f / 1024.0f) - mu * mu, 0.0f);
    float rs  = rsqrtf(var + 1e-5f);
    float4 gv = ((const float4*)g)[threadIdx.x];
    float4 bv = ((const float4*)bt)[threadIdx.x];
    short4v o;
    o.x = f2bf((v.x - mu) * rs * gv.x + bv.x);
    o.y = f2bf((v.y - mu) * rs * gv.y + bv.y);
    o.z = f2bf((v.z - mu) * rs * gv.z + bv.z);
    o.w = f2bf((v.w - mu) * rs * gv.w + bv.w);
    *(short4v*)(out + (size_t)row * 1024 + (size_t)threadIdx.x * 4) = o;
}

// ================= 256x256 8-wave phased GEMM core (unchanged) =================
template<int MODE>
DEV void gemm_core(const short* __restrict__ A, const short* __restrict__ B,
                   void* __restrict__ out, const float* __restrict__ resid,
                   int N, int K, int lda, int ldb, float osc, int bm, int bn) {
    __shared__ short lds[2 * 32768];
    const int tid = threadIdx.x;
    const int row0 = bm << 8, col0 = bn << 8;
    const int wid = tid >> 6, lane = tid & 63;
    const int wm = wid >> 2, wn = wid & 3;
    const int lr = lane & 15, lg = lane >> 4;
    const int NK = K >> 6;

    auto stage = [&](int kt, int which) {
        int d = kt & 1;
        const short* src; int rb; int ld;
        if (which < 2) { src = A; rb = row0; ld = lda; } else { src = B; rb = col0; ld = ldb; }
        int rhalf = (which & 1) << 7;
        short* dst = lds + d * 32768 + which * 8192;
        #pragma unroll
        for (int l = 0; l < 2; ++l) {
            int g = l * 512 + tid;
            int r = g >> 3, c = g & 7;
            gld16(src + (size_t)(rb + rhalf + r) * ld + kt * 64 + ((c ^ (r & 7)) << 3),
                  dst + g * 8);
        }
    };

    f32x4 acc[8][4] = {};

    stage(0, 0); stage(0, 1); stage(0, 2); stage(0, 3);
    if (NK > 1) {
        stage(1, 2); stage(1, 3);
        asm volatile("s_waitcnt vmcnt(4)" ::: "memory");
    } else {
        asm volatile("s_waitcnt vmcnt(0)" ::: "memory");
    }
    BAR();

    const int rBbase = (wn & 1) << 6;
    for (int t = 0; t < NK; ++t) {
        const short* bufA = lds + (t & 1) * 32768 + wm * 8192;
        const short* bufB = lds + (t & 1) * 32768 + 16384 + (wn >> 1) * 8192;
        bool st1 = (t + 1) < NK, st2 = (t + 2) < NK;
        short8 bf2[2][4];

        {
            short8 af[4];
            #pragma unroll
            for (int i = 0; i < 4; ++i) {
                int r = i * 16 + lr;
                af[i] = *(const short8*)(bufA + r * 64 + ((lg ^ (r & 7)) << 3));
            }
            #pragma unroll
            for (int j = 0; j < 4; ++j) {
                int rB = rBbase + j * 16 + lr;
                bf2[0][j] = *(const short8*)(bufB + rB * 64 + ((lg ^ (rB & 7)) << 3));
            }
            if (st1) stage(t + 1, 0);
            BAR();
            __builtin_amdgcn_s_setprio(1);
            #pragma unroll
            for (int i = 0; i < 4; ++i)
                #pragma unroll
                for (int j = 0; j < 4; ++j)
                    MFMA(acc[i][j], af[i], bf2[0][j]);
            __builtin_amdgcn_s_setprio(0);
            BAR();
        }
        {
            short8 af[4];
            #pragma unroll
            for (int i = 0; i < 4; ++i) {
                int r = i * 16 + lr;
                af[i] = *(const short8*)(bufA + r * 64 + (((4 + lg) ^ (r & 7)) << 3));
            }
            #pragma unroll
            for (int j = 0; j < 4; ++j) {
                int rB = rBbase + j * 16 + lr;
                bf2[1][j] = *(const short8*)(bufB + rB * 64 + (((4 + lg) ^ (rB & 7)) << 3));
            }
            if (st1) stage(t + 1, 1);
            BAR();
            __builtin_amdgcn_s_setprio(1);
            #pragma unroll
            for (int i = 0; i < 4; ++i)
                #pragma unroll
                for (int j = 0; j < 4; ++j)
                    MFMA(acc[i][j], af[i], bf2[1][j]);
            __builtin_amdgcn_s_setprio(0);
            BAR();
        }
        {
            short8 af[4];
            #pragma unroll
            for (int i = 0; i < 4; ++i) {
                int r = 64 + i * 16 + lr;
                af[i] = *(const short8*)(bufA + r * 64 + ((lg ^ (r & 7)) << 3));
            }
            if (st2) stage(t + 2, 2);
            BAR();
            __builtin_amdgcn_s_setprio(1);
            #pragma unroll
            for (int i = 0; i < 4; ++i)
                #pragma unroll
                for (int j = 0; j < 4; ++j)
                    MFMA(acc[4 + i][j], af[i], bf2[0][j]);
            __builtin_amdgcn_s_setprio(0);
            BAR();
        }
        {
            short8 af[4];
            #pragma unroll
            for (int i = 0; i < 4; ++i) {
                int r = 64 + i * 16 + lr;
                af[i] = *(const short8*)(bufA + r * 64 + (((4 + lg) ^ (r & 7)) << 3));
            }
            if (st2) stage(t + 2, 3);
            BAR();
            __builtin_amdgcn_s_setprio(1);
            #pragma unroll
            for (int i = 0; i < 4; ++i)
                #pragma unroll
                for (int j = 0; j < 4; ++j)
                    MFMA(acc[4 + i][j], af[i], bf2[1][j]);
            __builtin_amdgcn_s_setprio(0);
            if (st2)      asm volatile("s_waitcnt vmcnt(4)" ::: "memory");
            else if (st1) asm volatile("s_waitcnt vmcnt(0)" ::: "memory");
            BAR();
        }
    }
    asm volatile("s_nop 7\n\ts_nop 7");

    int orow0 = row0 + wm * 128, ocol0 = col0 + wn * 64;
    #pragma unroll
    for (int i = 0; i < 8; ++i)
        #pragma unroll
        for (int j = 0; j < 4; ++j)
            #pragma unroll
            for (int r = 0; r < 4; ++r) {
                int gr = orow0 + i * 16 + lg * 4 + r;
                int gc = ocol0 + j * 16 + lr;
                size_t off = (size_t)gr * N + gc;
                float v = acc[i][j][r];
                if constexpr (MODE == 1) {
                    ((float*)out)[off] = resid ? v + resid[off] : v;
                } else if constexpr (MODE == 2) {
                    ((short*)out)[off] = f2bf(gelu_f(v));
                } else {
                    ((short*)out)[off] = f2bf(v * osc);
                }
            }
}

__global__ __launch_bounds__(512, 2) void gemm_qkv(
    const short* __restrict__ XN, const short* __restrict__ CN,
    const short* __restrict__ Wq, const short* __restrict__ Wk, const short* __restrict__ Wv,
    short* __restrict__ QB, short* __restrict__ KB, short* __restrict__ VT, float qscale) {
    int sid = (blockIdx.x & 7) * 48 + (blockIdx.x >> 3);
    int sub = sid >> 7, i = sid & 127;
    const short *A, *B; short* o; float osc; int N, bm, bn;
    if (sub == 0)      { A = XN; B = Wq; o = QB; osc = qscale; N = 1024; bm = i >> 2; bn = i & 3; }
    else if (sub == 1) { A = CN; B = Wk; o = KB; osc = 1.0f;   N = 1024; bm = i >> 2; bn = i & 3; }
    else               { A = Wv; B = CN; o = VT; osc = 1.0f;   N = 8192; bm = i >> 5; bn = i & 31; }
    gemm_core<3>(A, B, o, nullptr, N, 1024, 1024, 1024, osc, bm, bn);
}

template<int MODE>
__global__ __launch_bounds__(512, 2) void gemm_std(const short* __restrict__ A,
                                                   const short* __restrict__ B,
                                                   void* __restrict__ out,
                                                   const float* __restrict__ resid,
                                                   int N, int K, float osc) {
    int cpx = gridDim.x >> 3;
    int sid = (blockIdx.x & 7) * cpx + (blockIdx.x >> 3);
    int nbn = N >> 8;
    int bm = sid / nbn, bn = sid % nbn;
    gemm_core<MODE>(A, B, out, resid, N, K, K, K, osc, bm, bn);
}

__global__ __launch_bounds__(512, 2) void gemm_ff2(const short* __restrict__ F1,
                                                   const short* __restrict__ W2,
                                                   float* __restrict__ dOut,
                                                   float* __restrict__ P2,
                                                   const float* __restrict__ X2) {
    int sid = (blockIdx.x & 7) * 32 + (blockIdx.x >> 3);
    int h = sid >> 7, i = sid & 127;
    int bm = i >> 2, bn = i & 3;
    const short* A = F1 + h * 2048;
    const short* B = W2 + h * 2048;
    float* o = h ? P2 : dOut;
    const float* r = h ? nullptr : X2;
    gemm_core<1>(A, B, o, r, 1024, 2048, 4096, 4096, 1.0f, bm, bn);
}

__global__ __launch_bounds__(256) void add_f32(float* __restrict__ dst,
                                               const float* __restrict__ src, int n4) {
    int i = blockIdx.x * 256 + threadIdx.x;
    int stride = gridDim.x * 256;
    for (; i < n4; i += stride) {
        float4 a = ((const float4*)dst)[i];
        float4 b = ((const float4*)src)[i];
        a.x += b.x; a.y += b.y; a.z += b.z; a.w += b.w;
        ((float4*)dst)[i] = a;
    }
}

// ---------------- Flash attention v4: k-permutation PV (zero-shuffle P) ----------------
// Swapped QK^T: lane (lr,lg) holds P[q=lr][k = fn*16 + lg*4 + r].
// PV uses permuted-k contract: pi(kb*32+lg*8+2w+e) = (2kb+(w>>1))*16 + lg*4 + 2(w&1)+e
// (bijection on [0,64)). A-frag = direct pack of the lane's own cvt_pk words (ZERO shuffles);
// V B-frag reads the pi'd columns via 2x ds_read_b64 per (kb,fn). Sum over k is permutation-
// invariant, so the result is exact.
__global__ __launch_bounds__(512, 6) void attn(const short* __restrict__ Q,
                                               const short* __restrict__ K,
                                               const short* __restrict__ Vt,
                                               short* __restrict__ O) {
    __shared__ short lK[2][64 * 64];
    __shared__ short lV[2][64 * 64];
    int tid = threadIdx.x;
    int sid = (blockIdx.x & 7) * 128 + (blockIdx.x >> 3);
    int bh = sid >> 4, qt = sid & 15;
    int b = bh >> 4, h = bh & 15;
    int wid = tid >> 6, lane = tid & 63;
    int lr = lane & 15, lg = lane >> 4;
    int q0 = qt * 128 + wid * 16;

    short8 qf[2];
    #pragma unroll
    for (int kb = 0; kb < 2; ++kb) {
        size_t roff = (size_t)(b * 2048 + q0 + lr) * 1024 + h * 64 + kb * 32 + lg * 8;
        qf[kb] = *(const short8*)(Q + roff);
    }

    f32x4 oacc[4] = {};
    float mrow = -1e30f, lsum = 0.0f;

    const short* Kb = K + (size_t)(b * 2048) * 1024 + h * 64;
    const short* Vb = Vt + (size_t)(h * 64) * 8192 + b * 2048;
    int albase = (lane & 48) >> 2;           // lg*4

    int sr = tid >> 3, scc = tid & 7;
    int ssl = scc ^ (sr & 7);
    auto stage = [&](int st, int d) {
        gld16(Kb + (size_t)(st * 64 + sr) * 1024 + ssl * 8, &lK[d][tid * 8]);
        gld16(Vb + (size_t)sr * 8192 + st * 64 + ssl * 8, &lV[d][tid * 8]);
    };

    stage(0, 0);
    asm volatile("s_waitcnt vmcnt(0)" ::: "memory");
    BAR();

    for (int st = 0; st < 32; ++st) {
        int d = st & 1;
        if (st + 1 < 32) stage(st + 1, d ^ 1);

        // S^T = K * Q^T : sc2[fn], row k = fn*16+lg*4+r, col q = lr
        f32x4 sc2[4] = {};
        #pragma unroll
        for (int kb = 0; kb < 2; ++kb) {
            short8 kf[4];
            #pragma unroll
            for (int fn = 0; fn < 4; ++fn) {
                int kr = fn * 16 + lr;
                kf[fn] = *(const short8*)(lK[d] + kr * 64 + (((kb * 4 + lg) ^ (kr & 7)) << 3));
            }
            #pragma unroll
            for (int fn = 0; fn < 4; ++fn)
                MFMA(sc2[fn], kf[fn], qf[kb]);
        }
        asm volatile("s_nop 7\n\ts_nop 7");

        // softmax: in-lane max tree (4 levels) + shfl16 + permlane32
        float m8[8];
        #pragma unroll
        for (int i = 0; i < 8; ++i)
            m8[i] = fmaxf(sc2[i >> 2][i & 3], sc2[(i + 8) >> 2][(i + 8) & 3]);
        float ma = fmaxf(fmaxf(m8[0], m8[1]), fmaxf(m8[2], m8[3]));
        float mb = fmaxf(fmaxf(m8[4], m8[5]), fmaxf(m8[6], m8[7]));
        float pm = fmaxf(ma, mb);
        pm = fmaxf(pm, __shfl_xor(pm, 16));
        pm = red32_max(pm);

        float al = 1.0f;
        float mn = mrow;
        if (!__all(pm <= mrow + 8.0f)) {
            mn = fmaxf(mrow, pm);
            al = exp2_hw(mrow - mn);
            mrow = mn;
            #pragma unroll
            for (int r = 0; r < 4; ++r) {
                float alr = __shfl(al, albase + r);
                #pragma unroll
                for (int fn = 0; fn < 4; ++fn) oacc[fn][r] *= alr;
            }
        }

        float p[4][4];
        #pragma unroll
        for (int fn = 0; fn < 4; ++fn)
            #pragma unroll
            for (int r = 0; r < 4; ++r)
                p[fn][r] = exp2_hw(sc2[fn][r] - mn);
        // sum tree
        float s8[8];
        #pragma unroll
        for (int i = 0; i < 8; ++i)
            s8[i] = p[i >> 2][i & 3] + p[(i + 8) >> 2][(i + 8) & 3];
        float sa = (s8[0] + s8[1]) + (s8[2] + s8[3]);
        float sb = (s8[4] + s8[5]) + (s8[6] + s8[7]);
        float ps = sa + sb;
        ps += __shfl_xor(ps, 16);
        ps = red32_add(ps);
        lsum = lsum * al + ps;

        // pack P pairs: U[fn][w'] = bf16x2 of (p[fn][2w'], p[fn][2w'+1]), k_nat = fn*16+lg*4+2w'+e
        unsigned U[4][2];
        #pragma unroll
        for (int fn = 0; fn < 4; ++fn) {
            U[fn][0] = cvt_pk_bf16(p[fn][0], p[fn][1]);
            U[fn][1] = cvt_pk_bf16(p[fn][2], p[fn][3]);
        }

        // PV with permuted-k: A-frag = lane-local pack; V read at pi'd columns (2x b64)
        #pragma unroll
        for (int kb = 0; kb < 2; ++kb) {
            uint4v pw;
            pw.x = U[kb * 2][0];
            pw.y = U[kb * 2][1];
            pw.z = U[kb * 2 + 1][0];
            pw.w = U[kb * 2 + 1][1];
            short8 pa = __builtin_bit_cast(short8, pw);

            #pragma unroll
            for (int fn = 0; fn < 4; ++fn) {
                int vr = fn * 16 + lr;
                int so_lo = (((kb * 4 + (lg >> 1)) ^ (vr & 7)) << 3) + ((lg & 1) << 2);
                int so_hi = (((kb * 4 + 2 + (lg >> 1)) ^ (vr & 7)) << 3) + ((lg & 1) << 2);
                union { short4v h[2]; short8 v; } u;
                u.h[0] = *(const short4v*)(lV[d] + vr * 64 + so_lo);
                u.h[1] = *(const short4v*)(lV[d] + vr * 64 + so_hi);
                MFMA(oacc[fn], pa, u.v);
            }
        }

        asm volatile("s_waitcnt vmcnt(0)" ::: "memory");
        BAR();
    }
    asm volatile("s_nop 7\n\ts_nop 7");

    #pragma unroll
    for (int r = 0; r < 4; ++r) {
        float linv = __shfl(lsum, albase + r);
        float inv = 1.0f / linv;
        #pragma unroll
        for (int fn = 0; fn < 4; ++fn) {
            size_t off = (size_t)(b * 2048 + q0 + lg * 4 + r) * 1024 + h * 64 + fn * 16 + lr;
            O[off] = f2bf(oacc[fn][r] * inv);
        }
    }
}

// ---------------- launch ----------------
extern "C" void kernel_launch(void* const* d_in, const int* in_sizes, int n_in,
                              void* d_out, int out_size, void* d_ws, size_t ws_size,
                              hipStream_t stream) {
    const float* x   = (const float*)d_in[0];
    const float* ctx = (const float*)d_in[1];
    const float* Wq  = (const float*)d_in[2];
    const float* Wk  = (const float*)d_in[3];
    const float* Wv  = (const float*)d_in[4];
    const float* Wo  = (const float*)d_in[5];
    const float* W1  = (const float*)d_in[6];
    const float* W2  = (const float*)d_in[7];
    const float* g1  = (const float*)d_in[8];
    const float* b1  = (const float*)d_in[9];
    const float* gc  = (const float*)d_in[10];
    const float* bc  = (const float*)d_in[11];
    const float* g2  = (const float*)d_in[12];
    const float* b2  = (const float*)d_in[13];

    char* ws = (char*)d_ws;
    const size_t OFF_W  = 0;
    const size_t OFF_XN = 25165824;
    const size_t OFF_CN = OFF_XN + 16777216;
    const size_t OFF_QB = OFF_CN + 16777216;
    const size_t OFF_KB = OFF_QB + 16777216;
    const size_t OFF_VT = OFF_KB + 16777216;
    const size_t OFF_X2 = OFF_VT + 16777216;
    const size_t OFF_F1 = OFF_X2 + 33554432;

    short* Wb = (short*)(ws + OFF_W);
    short* XN = (short*)(ws + OFF_XN);
    short* CN = (short*)(ws + OFF_CN);
    short* QB = (short*)(ws + OFF_QB);
    short* KB = (short*)(ws + OFF_KB);
    short* VT = (short*)(ws + OFF_VT);
    float* X2 = (float*)(ws + OFF_X2);
    short* F1 = (short*)(ws + OFF_F1);
    short* OB = XN;
    short* H  = CN;
    float* P2 = (float*)(ws + OFF_QB);

    const size_t WQo = 0, WKo = 1048576, WVo = 2097152, WOo = 3145728;
    const size_t W1o = 4194304, W2o = 8388608;
    const float QSCALE = 0.125f * 1.4426950408889634f;

    cvt_weights<<<12288, 256, 0, stream>>>(Wq, Wk, Wv, Wo, W1, W2, Wb);
    ln_bf16<<<8192, 256, 0, stream>>>(x, g1, b1, XN);
    ln_bf16<<<8192, 256, 0, stream>>>(ctx, gc, bc, CN);
    gemm_qkv<<<384, 512, 0, stream>>>(XN, CN, Wb + WQo, Wb + WKo, Wb + WVo, QB, KB, VT, QSCALE);
    attn<<<1024, 512, 0, stream>>>(QB, KB, VT, OB);
    gemm_std<1><<<128, 512, 0, stream>>>(OB, Wb + WOo, X2, x, 1024, 1024, 1.0f);
    ln_bf16<<<8192, 256, 0, stream>>>(X2, g2, b2, H);
    gemm_std<2><<<512, 512, 0, stream>>>(H, Wb + W1o, F1, nullptr, 4096, 1024, 1.0f);
    gemm_ff2<<<256, 512, 0, stream>>>(F1, Wb + W2o, (float*)d_out, P2, X2);
    add_f32<<<2048, 256, 0, stream>>>((float*)d_out, P2, 2097152);
}

// Round 13
// 438.641 us; speedup vs baseline: 1.1181x; 1.0339x over previous
//
#include <hip/hip_runtime.h>
#include <cstdint>
#include <cstddef>

typedef __attribute__((ext_vector_type(8))) short short8;
typedef __attribute__((ext_vector_type(4))) short short4v;
typedef __attribute__((ext_vector_type(4))) float f32x4;
typedef __attribute__((ext_vector_type(4))) unsigned uint4v;

#define DEV static __device__ __forceinline__

DEV short f2bf(float f) {
    unsigned u = __builtin_bit_cast(unsigned, f);
    unsigned r = (u + 0x7fffu + ((u >> 16) & 1u)) >> 16;
    return (short)r;
}

DEV unsigned cvt_pk_bf16(float a, float b) {
    unsigned r;
    asm("v_cvt_pk_bf16_f32 %0, %1, %2" : "=v"(r) : "v"(a), "v"(b));
    return r;
}

DEV float exp2_hw(float x) {
    float r;
    asm("v_exp_f32 %0, %1" : "=v"(r) : "v"(x));
    return r;
}

DEV float rcp_hw(float x) {
    float r;
    asm("v_rcp_f32 %0, %1" : "=v"(r) : "v"(x));
    return r;
}

// exact-enough GELU: tanh form, exp2-based. max abs err ~3e-4.
DEV float gelu_f(float v) {
    float t  = v * (1.0f + 0.044715f * v * v);
    float e  = exp2_hw(fminf(2.3022082f * t, 126.0f));
    return v * e * rcp_hw(e + 1.0f);
}

DEV void gld16(const void* g, void* l) {
    __builtin_amdgcn_global_load_lds((const __attribute__((address_space(1))) void*)g,
                                     (__attribute__((address_space(3))) void*)l, 16, 0, 0);
}

#define MFMA(c, a, b) asm volatile("v_mfma_f32_16x16x32_bf16 %0, %1, %2, %0" : "+v"(c) : "v"(a), "v"(b))
#define BAR() asm volatile("s_barrier" ::: "memory")

// cross-32 reduction helpers: v_permlane32_swap_b32 semantics (pinned R9/R10): D.hi <-> S.lo
DEV float red32_max(float v) {
    float a = v, b = v;
    asm volatile("v_permlane32_swap_b32 %0, %1" : "+v"(a), "+v"(b));
    return fmaxf(a, b);
}
DEV float red32_add(float v) {
    float a = v, b = v;
    asm volatile("v_permlane32_swap_b32 %0, %1" : "+v"(a), "+v"(b));
    return a + b;
}

// ---------------- LN row body (fp32 in -> bf16 out), 256 threads ----------------
DEV void ln_row(const float* __restrict__ x, const float* __restrict__ g,
                const float* __restrict__ bt, short* __restrict__ out, int row) {
    const float4* xr = (const float4*)(x + (size_t)row * 1024);
    float4 v = xr[threadIdx.x];
    float s  = v.x + v.y + v.z + v.w;
    float s2 = v.x*v.x + v.y*v.y + v.z*v.z + v.w*v.w;
    #pragma unroll
    for (int m = 1; m < 64; m <<= 1) { s += __shfl_xor(s, m); s2 += __shfl_xor(s2, m); }
    __shared__ float red[8];
    int wid = threadIdx.x >> 6;
    if ((threadIdx.x & 63) == 0) { red[wid] = s; red[4 + wid] = s2; }
    __syncthreads();
    s  = red[0] + red[1] + red[2] + red[3];
    s2 = red[4] + red[5] + red[6] + red[7];
    float mu  = s * (1.0f / 1024.0f);
    float var = fmaxf(s2 * (1.0f / 1024.0f) - mu * mu, 0.0f);
    float rs  = rsqrtf(var + 1e-5f);
    float4 gv = ((const float4*)g)[threadIdx.x];
    float4 bv = ((const float4*)bt)[threadIdx.x];
    short4v o;
    o.x = f2bf((v.x - mu) * rs * gv.x + bv.x);
    o.y = f2bf((v.y - mu) * rs * gv.y + bv.y);
    o.z = f2bf((v.z - mu) * rs * gv.z + bv.z);
    o.w = f2bf((v.w - mu) * rs * gv.w + bv.w);
    *(short4v*)(out + (size_t)row * 1024 + (size_t)threadIdx.x * 4) = o;
}

// ---------------- fused prep: weight cvt (12288 blk) + LN(x) (8192) + LN(ctx) (8192) ----------------
__global__ __launch_bounds__(256) void prep(
    const float* __restrict__ wq, const float* __restrict__ wk,
    const float* __restrict__ wv, const float* __restrict__ wo,
    const float* __restrict__ w1, const float* __restrict__ w2,
    short* __restrict__ dstW,
    const float* __restrict__ x,   const float* __restrict__ g1, const float* __restrict__ b1,
    short* __restrict__ XN,
    const float* __restrict__ ctx, const float* __restrict__ gc, const float* __restrict__ bc,
    short* __restrict__ CN) {
    int bid = blockIdx.x;
    if (bid < 12288) {
        long long gid = (long long)bid * 256 + threadIdx.x;
        long long i4 = gid * 4;
        const float* src; long long loc;
        if (i4 < (4LL << 20)) {
            int s = (int)(i4 >> 20);
            src = (s == 0) ? wq : (s == 1) ? wk : (s == 2) ? wv : wo;
            loc = i4 & ((1LL << 20) - 1);
        } else {
            long long r = i4 - (4LL << 20);
            int s = (int)(r >> 22);
            src = s ? w2 : w1;
            loc = r & ((1LL << 22) - 1);
        }
        float4 v = *(const float4*)(src + loc);
        short4v o;
        o.x = f2bf(v.x); o.y = f2bf(v.y); o.z = f2bf(v.z); o.w = f2bf(v.w);
        *(short4v*)(dstW + i4) = o;
    } else if (bid < 12288 + 8192) {
        ln_row(x, g1, b1, XN, bid - 12288);
    } else {
        ln_row(ctx, gc, bc, CN, bid - 20480);
    }
}

__global__ __launch_bounds__(256) void ln_bf16(const float* __restrict__ x,
                                               const float* __restrict__ g,
                                               const float* __restrict__ bt,
                                               short* __restrict__ out) {
    ln_row(x, g, bt, out, blockIdx.x);
}

// ================= 256x256 8-wave phased GEMM core (unchanged) =================
template<int MODE>
DEV void gemm_core(const short* __restrict__ A, const short* __restrict__ B,
                   void* __restrict__ out, const float* __restrict__ resid,
                   int N, int K, int lda, int ldb, float osc, int bm, int bn) {
    __shared__ short lds[2 * 32768];
    const int tid = threadIdx.x;
    const int row0 = bm << 8, col0 = bn << 8;
    const int wid = tid >> 6, lane = tid & 63;
    const int wm = wid >> 2, wn = wid & 3;
    const int lr = lane & 15, lg = lane >> 4;
    const int NK = K >> 6;

    auto stage = [&](int kt, int which) {
        int d = kt & 1;
        const short* src; int rb; int ld;
        if (which < 2) { src = A; rb = row0; ld = lda; } else { src = B; rb = col0; ld = ldb; }
        int rhalf = (which & 1) << 7;
        short* dst = lds + d * 32768 + which * 8192;
        #pragma unroll
        for (int l = 0; l < 2; ++l) {
            int g = l * 512 + tid;
            int r = g >> 3, c = g & 7;
            gld16(src + (size_t)(rb + rhalf + r) * ld + kt * 64 + ((c ^ (r & 7)) << 3),
                  dst + g * 8);
        }
    };

    f32x4 acc[8][4] = {};

    stage(0, 0); stage(0, 1); stage(0, 2); stage(0, 3);
    if (NK > 1) {
        stage(1, 2); stage(1, 3);
        asm volatile("s_waitcnt vmcnt(4)" ::: "memory");
    } else {
        asm volatile("s_waitcnt vmcnt(0)" ::: "memory");
    }
    BAR();

    const int rBbase = (wn & 1) << 6;
    for (int t = 0; t < NK; ++t) {
        const short* bufA = lds + (t & 1) * 32768 + wm * 8192;
        const short* bufB = lds + (t & 1) * 32768 + 16384 + (wn >> 1) * 8192;
        bool st1 = (t + 1) < NK, st2 = (t + 2) < NK;
        short8 bf2[2][4];

        {
            short8 af[4];
            #pragma unroll
            for (int i = 0; i < 4; ++i) {
                int r = i * 16 + lr;
                af[i] = *(const short8*)(bufA + r * 64 + ((lg ^ (r & 7)) << 3));
            }
            #pragma unroll
            for (int j = 0; j < 4; ++j) {
                int rB = rBbase + j * 16 + lr;
                bf2[0][j] = *(const short8*)(bufB + rB * 64 + ((lg ^ (rB & 7)) << 3));
            }
            if (st1) stage(t + 1, 0);
            BAR();
            __builtin_amdgcn_s_setprio(1);
            #pragma unroll
            for (int i = 0; i < 4; ++i)
                #pragma unroll
                for (int j = 0; j < 4; ++j)
                    MFMA(acc[i][j], af[i], bf2[0][j]);
            __builtin_amdgcn_s_setprio(0);
            BAR();
        }
        {
            short8 af[4];
            #pragma unroll
            for (int i = 0; i < 4; ++i) {
                int r = i * 16 + lr;
                af[i] = *(const short8*)(bufA + r * 64 + (((4 + lg) ^ (r & 7)) << 3));
            }
            #pragma unroll
            for (int j = 0; j < 4; ++j) {
                int rB = rBbase + j * 16 + lr;
                bf2[1][j] = *(const short8*)(bufB + rB * 64 + (((4 + lg) ^ (rB & 7)) << 3));
            }
            if (st1) stage(t + 1, 1);
            BAR();
            __builtin_amdgcn_s_setprio(1);
            #pragma unroll
            for (int i = 0; i < 4; ++i)
                #pragma unroll
                for (int j = 0; j < 4; ++j)
                    MFMA(acc[i][j], af[i], bf2[1][j]);
            __builtin_amdgcn_s_setprio(0);
            BAR();
        }
        {
            short8 af[4];
            #pragma unroll
            for (int i = 0; i < 4; ++i) {
                int r = 64 + i * 16 + lr;
                af[i] = *(const short8*)(bufA + r * 64 + ((lg ^ (r & 7)) << 3));
            }
            if (st2) stage(t + 2, 2);
            BAR();
            __builtin_amdgcn_s_setprio(1);
            #pragma unroll
            for (int i = 0; i < 4; ++i)
                #pragma unroll
                for (int j = 0; j < 4; ++j)
                    MFMA(acc[4 + i][j], af[i], bf2[0][j]);
            __builtin_amdgcn_s_setprio(0);
            BAR();
        }
        {
            short8 af[4];
            #pragma unroll
            for (int i = 0; i < 4; ++i) {
                int r = 64 + i * 16 + lr;
                af[i] = *(const short8*)(bufA + r * 64 + (((4 + lg) ^ (r & 7)) << 3));
            }
            if (st2) stage(t + 2, 3);
            BAR();
            __builtin_amdgcn_s_setprio(1);
            #pragma unroll
            for (int i = 0; i < 4; ++i)
                #pragma unroll
                for (int j = 0; j < 4; ++j)
                    MFMA(acc[4 + i][j], af[i], bf2[1][j]);
            __builtin_amdgcn_s_setprio(0);
            if (st2)      asm volatile("s_waitcnt vmcnt(4)" ::: "memory");
            else if (st1) asm volatile("s_waitcnt vmcnt(0)" ::: "memory");
            BAR();
        }
    }
    asm volatile("s_nop 7\n\ts_nop 7");

    int orow0 = row0 + wm * 128, ocol0 = col0 + wn * 64;
    #pragma unroll
    for (int i = 0; i < 8; ++i)
        #pragma unroll
        for (int j = 0; j < 4; ++j)
            #pragma unroll
            for (int r = 0; r < 4; ++r) {
                int gr = orow0 + i * 16 + lg * 4 + r;
                int gc = ocol0 + j * 16 + lr;
                size_t off = (size_t)gr * N + gc;
                float v = acc[i][j][r];
                if constexpr (MODE == 1) {
                    ((float*)out)[off] = resid ? v + resid[off] : v;
                } else if constexpr (MODE == 2) {
                    ((short*)out)[off] = f2bf(gelu_f(v));
                } else {
                    ((short*)out)[off] = f2bf(v * osc);
                }
            }
}

__global__ __launch_bounds__(512, 2) void gemm_qkv(
    const short* __restrict__ XN, const short* __restrict__ CN,
    const short* __restrict__ Wq, const short* __restrict__ Wk, const short* __restrict__ Wv,
    short* __restrict__ QB, short* __restrict__ KB, short* __restrict__ VT, float qscale) {
    int sid = (blockIdx.x & 7) * 48 + (blockIdx.x >> 3);
    int sub = sid >> 7, i = sid & 127;
    const short *A, *B; short* o; float osc; int N, bm, bn;
    if (sub == 0)      { A = XN; B = Wq; o = QB; osc = qscale; N = 1024; bm = i >> 2; bn = i & 3; }
    else if (sub == 1) { A = CN; B = Wk; o = KB; osc = 1.0f;   N = 1024; bm = i >> 2; bn = i & 3; }
    else               { A = Wv; B = CN; o = VT; osc = 1.0f;   N = 8192; bm = i >> 5; bn = i & 31; }
    gemm_core<3>(A, B, o, nullptr, N, 1024, 1024, 1024, osc, bm, bn);
}

template<int MODE>
__global__ __launch_bounds__(512, 2) void gemm_std(const short* __restrict__ A,
                                                   const short* __restrict__ B,
                                                   void* __restrict__ out,
                                                   const float* __restrict__ resid,
                                                   int N, int K, float osc) {
    int cpx = gridDim.x >> 3;
    int sid = (blockIdx.x & 7) * cpx + (blockIdx.x >> 3);
    int nbn = N >> 8;
    int bm = sid / nbn, bn = sid % nbn;
    gemm_core<MODE>(A, B, out, resid, N, K, K, K, osc, bm, bn);
}

__global__ __launch_bounds__(512, 2) void gemm_ff2(const short* __restrict__ F1,
                                                   const short* __restrict__ W2,
                                                   float* __restrict__ dOut,
                                                   float* __restrict__ P2,
                                                   const float* __restrict__ X2) {
    int sid = (blockIdx.x & 7) * 32 + (blockIdx.x >> 3);
    int h = sid >> 7, i = sid & 127;
    int bm = i >> 2, bn = i & 3;
    const short* A = F1 + h * 2048;
    const short* B = W2 + h * 2048;
    float* o = h ? P2 : dOut;
    const float* r = h ? nullptr : X2;
    gemm_core<1>(A, B, o, r, 1024, 2048, 4096, 4096, 1.0f, bm, bn);
}

__global__ __launch_bounds__(256) void add_f32(float* __restrict__ dst,
                                               const float* __restrict__ src, int n4) {
    int i = blockIdx.x * 256 + threadIdx.x;
    int stride = gridDim.x * 256;
    for (; i < n4; i += stride) {
        float4 a = ((const float4*)dst)[i];
        float4 b = ((const float4*)src)[i];
        a.x += b.x; a.y += b.y; a.z += b.z; a.w += b.w;
        ((float4*)dst)[i] = a;
    }
}

// ---------------- Flash attention v6: fm=2 (32 q/wave, QBLK=256) + R11's proven V path ----------------
// ISOLATION ROUND: only change vs R11-passing attn is the fm=2 widening (and grid 512).
// V store/read = R11's XOR 16B-slot swizzle (HW-validated). Zero-shuffle P (k-permutation PV,
// pi identical to R11's). 512 blocks (64 bh x 8 qt) = one full round at 2 blocks/CU.
__global__ __launch_bounds__(512, 4) void attn(const short* __restrict__ Q,
                                               const short* __restrict__ K,
                                               const short* __restrict__ Vt,
                                               short* __restrict__ O) {
    __shared__ short lK[2][64 * 64];
    __shared__ short lV[2][64 * 64];
    int tid = threadIdx.x;
    int sid = (blockIdx.x & 7) * 64 + (blockIdx.x >> 3);
    int bh = sid >> 3, qt = sid & 7;
    int b = bh >> 4, h = bh & 15;
    int wid = tid >> 6, lane = tid & 63;
    int lr = lane & 15, lg = lane >> 4;
    int q0 = qt * 256 + wid * 32;

    short8 qf[2][2];
    #pragma unroll
    for (int fm = 0; fm < 2; ++fm)
        #pragma unroll
        for (int kb = 0; kb < 2; ++kb) {
            size_t roff = (size_t)(b * 2048 + q0 + fm * 16 + lr) * 1024 + h * 64 + kb * 32 + lg * 8;
            qf[fm][kb] = *(const short8*)(Q + roff);
        }

    f32x4 oacc[2][4] = {};
    float mrow[2] = { -1e30f, -1e30f };
    float lsum[2] = { 0.0f, 0.0f };

    const short* Kb = K + (size_t)(b * 2048) * 1024 + h * 64;
    const short* Vb = Vt + (size_t)(h * 64) * 8192 + b * 2048;
    int albase = (lane & 48) >> 2;           // lg*4

    int sr = tid >> 3, scc = tid & 7;
    int ssl = scc ^ (sr & 7);                // R11's validated store swizzle (K and V)
    auto stage = [&](int st, int d) {
        gld16(Kb + (size_t)(st * 64 + sr) * 1024 + ssl * 8, &lK[d][tid * 8]);
        gld16(Vb + (size_t)sr * 8192 + st * 64 + ssl * 8, &lV[d][tid * 8]);
    };

    stage(0, 0);
    asm volatile("s_waitcnt vmcnt(0)" ::: "memory");
    BAR();

    for (int st = 0; st < 32; ++st) {
        int d = st & 1;
        if (st + 1 < 32) stage(st + 1, d ^ 1);

        // S^T = K * Q^T : sc2[fn][fm], row k = fn*16+lg*4+r, col q = fm*16+lr
        f32x4 sc2[4][2] = {};
        #pragma unroll
        for (int kb = 0; kb < 2; ++kb) {
            short8 kf[4];
            #pragma unroll
            for (int fn = 0; fn < 4; ++fn) {
                int kr = fn * 16 + lr;
                kf[fn] = *(const short8*)(lK[d] + kr * 64 + (((kb * 4 + lg) ^ (kr & 7)) << 3));
            }
            #pragma unroll
            for (int fn = 0; fn < 4; ++fn)
                #pragma unroll
                for (int fm = 0; fm < 2; ++fm)
                    MFMA(sc2[fn][fm], kf[fn], qf[fm][kb]);
        }
        asm volatile("s_nop 7\n\ts_nop 7");

        short8 pa[2][2];
        #pragma unroll
        for (int fm = 0; fm < 2; ++fm) {
            // in-lane max tree + shfl16 + permlane32
            float m8[8];
            #pragma unroll
            for (int i = 0; i < 8; ++i)
                m8[i] = fmaxf(sc2[i >> 2][fm][i & 3], sc2[(i + 8) >> 2][fm][(i + 8) & 3]);
            float ma = fmaxf(fmaxf(m8[0], m8[1]), fmaxf(m8[2], m8[3]));
            float mb = fmaxf(fmaxf(m8[4], m8[5]), fmaxf(m8[6], m8[7]));
            float pm = fmaxf(ma, mb);
            pm = fmaxf(pm, __shfl_xor(pm, 16));
            pm = red32_max(pm);

            float al = 1.0f;
            float mn = mrow[fm];
            if (!__all(pm <= mn + 8.0f)) {
                mn = fmaxf(mn, pm);
                al = exp2_hw(mrow[fm] - mn);
                mrow[fm] = mn;
                #pragma unroll
                for (int r = 0; r < 4; ++r) {
                    float alr = __shfl(al, albase + r);
                    #pragma unroll
                    for (int fn = 0; fn < 4; ++fn) oacc[fm][fn][r] *= alr;
                }
            }

            float p[4][4];
            #pragma unroll
            for (int fn = 0; fn < 4; ++fn)
                #pragma unroll
                for (int r = 0; r < 4; ++r)
                    p[fn][r] = exp2_hw(sc2[fn][fm][r] - mn);
            float s8[8];
            #pragma unroll
            for (int i = 0; i < 8; ++i)
                s8[i] = p[i >> 2][i & 3] + p[(i + 8) >> 2][(i + 8) & 3];
            float ps = ((s8[0] + s8[1]) + (s8[2] + s8[3])) + ((s8[4] + s8[5]) + (s8[6] + s8[7]));
            ps += __shfl_xor(ps, 16);
            ps = red32_add(ps);
            lsum[fm] = lsum[fm] * al + ps;

            uint4v pw0, pw1;
            pw0.x = cvt_pk_bf16(p[0][0], p[0][1]);
            pw0.y = cvt_pk_bf16(p[0][2], p[0][3]);
            pw0.z = cvt_pk_bf16(p[1][0], p[1][1]);
            pw0.w = cvt_pk_bf16(p[1][2], p[1][3]);
            pw1.x = cvt_pk_bf16(p[2][0], p[2][1]);
            pw1.y = cvt_pk_bf16(p[2][2], p[2][3]);
            pw1.z = cvt_pk_bf16(p[3][0], p[3][1]);
            pw1.w = cvt_pk_bf16(p[3][2], p[3][3]);
            pa[fm][0] = __builtin_bit_cast(short8, pw0);
            pa[fm][1] = __builtin_bit_cast(short8, pw1);
        }

        // PV: R11's validated V read (XOR 16B-slot + 8B sub-offset), vf shared across fm
        #pragma unroll
        for (int kb = 0; kb < 2; ++kb) {
            short8 vf[4];
            #pragma unroll
            for (int fn = 0; fn < 4; ++fn) {
                int vr = fn * 16 + lr;
                int so_lo = (((kb * 4 + (lg >> 1)) ^ (vr & 7)) << 3) + ((lg & 1) << 2);
                int so_hi = (((kb * 4 + 2 + (lg >> 1)) ^ (vr & 7)) << 3) + ((lg & 1) << 2);
                union { short4v hv[2]; short8 v; } u;
                u.hv[0] = *(const short4v*)(lV[d] + vr * 64 + so_lo);
                u.hv[1] = *(const short4v*)(lV[d] + vr * 64 + so_hi);
                vf[fn] = u.v;
            }
            #pragma unroll
            for (int fn = 0; fn < 4; ++fn)
                #pragma unroll
                for (int fm = 0; fm < 2; ++fm)
                    MFMA(oacc[fm][fn], pa[fm][kb], vf[fn]);
        }

        asm volatile("s_waitcnt vmcnt(0)" ::: "memory");
        BAR();
    }
    asm volatile("s_nop 7\n\ts_nop 7");

    #pragma unroll
    for (int fm = 0; fm < 2; ++fm)
        #pragma unroll
        for (int r = 0; r < 4; ++r) {
            float linv = __shfl(lsum[fm], albase + r);
            float inv = 1.0f / linv;
            #pragma unroll
            for (int fn = 0; fn < 4; ++fn) {
                size_t off = (size_t)(b * 2048 + q0 + fm * 16 + lg * 4 + r) * 1024 + h * 64 + fn * 16 + lr;
                O[off] = f2bf(oacc[fm][fn][r] * inv);
            }
        }
}

// ---------------- launch ----------------
extern "C" void kernel_launch(void* const* d_in, const int* in_sizes, int n_in,
                              void* d_out, int out_size, void* d_ws, size_t ws_size,
                              hipStream_t stream) {
    const float* x   = (const float*)d_in[0];
    const float* ctx = (const float*)d_in[1];
    const float* Wq  = (const float*)d_in[2];
    const float* Wk  = (const float*)d_in[3];
    const float* Wv  = (const float*)d_in[4];
    const float* Wo  = (const float*)d_in[5];
    const float* W1  = (const float*)d_in[6];
    const float* W2  = (const float*)d_in[7];
    const float* g1  = (const float*)d_in[8];
    const float* b1  = (const float*)d_in[9];
    const float* gc  = (const float*)d_in[10];
    const float* bc  = (const float*)d_in[11];
    const float* g2  = (const float*)d_in[12];
    const float* b2  = (const float*)d_in[13];

    char* ws = (char*)d_ws;
    const size_t OFF_W  = 0;
    const size_t OFF_XN = 25165824;
    const size_t OFF_CN = OFF_XN + 16777216;
    const size_t OFF_QB = OFF_CN + 16777216;
    const size_t OFF_KB = OFF_QB + 16777216;
    const size_t OFF_VT = OFF_KB + 16777216;
    const size_t OFF_X2 = OFF_VT + 16777216;
    const size_t OFF_F1 = OFF_X2 + 33554432;

    short* Wb = (short*)(ws + OFF_W);
    short* XN = (short*)(ws + OFF_XN);
    short* CN = (short*)(ws + OFF_CN);
    short* QB = (short*)(ws + OFF_QB);
    short* KB = (short*)(ws + OFF_KB);
    short* VT = (short*)(ws + OFF_VT);
    float* X2 = (float*)(ws + OFF_X2);
    short* F1 = (short*)(ws + OFF_F1);
    short* OB = XN;
    short* H  = CN;
    float* P2 = (float*)(ws + OFF_QB);

    const size_t WQo = 0, WKo = 1048576, WVo = 2097152, WOo = 3145728;
    const size_t W1o = 4194304, W2o = 8388608;
    const float QSCALE = 0.125f * 1.4426950408889634f;

    prep<<<28672, 256, 0, stream>>>(Wq, Wk, Wv, Wo, W1, W2, Wb,
                                    x, g1, b1, XN, ctx, gc, bc, CN);
    gemm_qkv<<<384, 512, 0, stream>>>(XN, CN, Wb + WQo, Wb + WKo, Wb + WVo, QB, KB, VT, QSCALE);
    attn<<<512, 512, 0, stream>>>(QB, KB, VT, OB);
    gemm_std<1><<<128, 512, 0, stream>>>(OB, Wb + WOo, X2, x, 1024, 1024, 1.0f);
    ln_bf16<<<8192, 256, 0, stream>>>(X2, g2, b2, H);
    gemm_std<2><<<512, 512, 0, stream>>>(H, Wb + W1o, F1, nullptr, 4096, 1024, 1.0f);
    gemm_ff2<<<256, 512, 0, stream>>>(F1, Wb + W2o, (float*)d_out, P2, X2);
    add_f32<<<2048, 256, 0, stream>>>((float*)d_out, P2, 2097152);
}